// Round 1
// baseline (674.824 us; speedup 1.0000x reference)
//
#include <hip/hip_runtime.h>
#include <hip/hip_bf16.h>
#include <cstdint>

// Problem constants (B=2, H=16 -> 32 heads)
#define LQ_N   2048
#define LK_N   2048
#define DD     128
#define NHEADS 32
#define QBLK   64
#define KVBLK  32
#define SCALE  0.08838834764831845f   // 1/sqrt(128)

// LDS strides in bf16 elements; chosen so row byte-stride is a multiple of 16
// (keeps ds_read_b128 aligned) and start banks spread (<=2-way conflicts).
#define KSTRIDE  136   // 128 + 8  -> 272 B/row
#define VTSTRIDE 40    // 32 + 8   -> 80 B/row
#define PSTRIDE  40    // 32 + 8   -> 80 B/row

typedef __attribute__((ext_vector_type(8))) short bf16x8;
typedef __attribute__((ext_vector_type(4))) float f32x4;

__device__ inline unsigned short f2bf(float f) {
    union { float f; unsigned u; } x; x.f = f;
    unsigned r = (x.u + 0x7fffu + ((x.u >> 16) & 1u)) >> 16;  // RNE
    return (unsigned short)r;
}

__global__ __launch_bounds__(256, 2)
void attn_fwd_kernel(const float* __restrict__ Q, const float* __restrict__ K,
                     const float* __restrict__ V, float* __restrict__ O)
{
    __shared__ unsigned short k_lds[KVBLK * KSTRIDE];    // K tile, bf16, row-major [32][128]
    __shared__ unsigned short vt_lds[DD * VTSTRIDE];     // V tile transposed, bf16 [128][32]
    __shared__ unsigned short p_lds[4 * 16 * PSTRIDE];   // per-wave P tile [16][32]

    const int tid  = threadIdx.x;
    const int lane = tid & 63;
    const int wave = tid >> 6;
    const int head = blockIdx.y;   // 0..31
    const int qb   = blockIdx.x;   // 0..31

    const float* Qh = Q + (size_t)head * LQ_N * DD;
    const float* Kh = K + (size_t)head * LK_N * DD;
    const float* Vh = V + (size_t)head * LK_N * DD;
    float*       Oh = O + (size_t)head * LQ_N * DD;

    const int r16 = lane & 15;   // A/B fragment row; C fragment col
    const int g   = lane >> 4;   // 0..3

    // ---- Load Q fragments (scale folded in). Wave owns rows qb*64 + wave*16 + [0,16).
    // A-frag: lane holds Q[r16][32*kt + 8*g + j], j=0..7
    const int qrow = qb * QBLK + wave * 16 + r16;
    bf16x8 qf[4];
    {
        const float* qp = Qh + (size_t)qrow * DD + 8 * g;
        #pragma unroll
        for (int kt = 0; kt < 4; ++kt) {
            float4 a = *(const float4*)(qp + 32 * kt);
            float4 b = *(const float4*)(qp + 32 * kt + 4);
            bf16x8 t;
            t[0] = (short)f2bf(a.x * SCALE); t[1] = (short)f2bf(a.y * SCALE);
            t[2] = (short)f2bf(a.z * SCALE); t[3] = (short)f2bf(a.w * SCALE);
            t[4] = (short)f2bf(b.x * SCALE); t[5] = (short)f2bf(b.y * SCALE);
            t[6] = (short)f2bf(b.z * SCALE); t[7] = (short)f2bf(b.w * SCALE);
            qf[kt] = t;
        }
    }

    f32x4 o_acc[8];
    #pragma unroll
    for (int dt = 0; dt < 8; ++dt) o_acc[dt] = (f32x4){0.f, 0.f, 0.f, 0.f};
    float m_run[4], l_run[4];
    #pragma unroll
    for (int r = 0; r < 4; ++r) { m_run[r] = -1e30f; l_run[r] = 0.f; }

    for (int kv = 0; kv < LK_N / KVBLK; ++kv) {
        const float* Kt = Kh + (size_t)kv * KVBLK * DD;
        const float* Vt = Vh + (size_t)kv * KVBLK * DD;

        __syncthreads();   // previous iteration's readers done before restaging

        // ---- Stage K tile: 32x128 fp32 -> bf16 LDS (coalesced float4 loads)
        #pragma unroll
        for (int i = 0; i < 4; ++i) {
            int f = tid + 256 * i;           // float4 index, 1024 total
            int row = f >> 5;                // 32 float4 per row
            int colf = f & 31;
            float4 x = *(const float4*)(Kt + (size_t)row * DD + colf * 4);
            ushort4 pk;
            pk.x = f2bf(x.x); pk.y = f2bf(x.y); pk.z = f2bf(x.z); pk.w = f2bf(x.w);
            *(ushort4*)(&k_lds[row * KSTRIDE + colf * 4]) = pk;
        }
        // ---- Stage V tile transposed: V[r][c] -> vt_lds[c][r]
        #pragma unroll
        for (int i = 0; i < 4; ++i) {
            int f = tid + 256 * i;
            int row = f >> 5;
            int colf = f & 31;
            float4 x = *(const float4*)(Vt + (size_t)row * DD + colf * 4);
            vt_lds[(colf * 4 + 0) * VTSTRIDE + row] = f2bf(x.x);
            vt_lds[(colf * 4 + 1) * VTSTRIDE + row] = f2bf(x.y);
            vt_lds[(colf * 4 + 2) * VTSTRIDE + row] = f2bf(x.z);
            vt_lds[(colf * 4 + 3) * VTSTRIDE + row] = f2bf(x.w);
        }
        __syncthreads();

        // ---- S = Q K^T for this wave's 16 rows x 32 kv cols
        f32x4 s0 = (f32x4){0.f, 0.f, 0.f, 0.f};
        f32x4 s1 = (f32x4){0.f, 0.f, 0.f, 0.f};
        #pragma unroll
        for (int kt = 0; kt < 4; ++kt) {
            bf16x8 kf0 = *(const bf16x8*)&k_lds[(r16)      * KSTRIDE + 32 * kt + 8 * g];
            bf16x8 kf1 = *(const bf16x8*)&k_lds[(16 + r16) * KSTRIDE + 32 * kt + 8 * g];
            s0 = __builtin_amdgcn_mfma_f32_16x16x32_bf16(qf[kt], kf0, s0, 0, 0, 0);
            s1 = __builtin_amdgcn_mfma_f32_16x16x32_bf16(qf[kt], kf1, s1, 0, 0, 0);
        }

        // ---- online softmax (rows 4*g + r, col r16 / 16+r16)
        float alpha[4];
        f32x4 p0, p1;
        #pragma unroll
        for (int r = 0; r < 4; ++r) {
            float t = fmaxf(s0[r], s1[r]);
            t = fmaxf(t, __shfl_xor(t, 1));
            t = fmaxf(t, __shfl_xor(t, 2));
            t = fmaxf(t, __shfl_xor(t, 4));
            t = fmaxf(t, __shfl_xor(t, 8));
            float mn = fmaxf(m_run[r], t);
            alpha[r] = __expf(m_run[r] - mn);
            m_run[r] = mn;
            p0[r] = __expf(s0[r] - mn);
            p1[r] = __expf(s1[r] - mn);
            float s = p0[r] + p1[r];
            s += __shfl_xor(s, 1);
            s += __shfl_xor(s, 2);
            s += __shfl_xor(s, 4);
            s += __shfl_xor(s, 8);
            l_run[r] = l_run[r] * alpha[r] + s;
        }

        // ---- P -> LDS (per-wave tile), then read back as A-fragment
        unsigned short* pw = &p_lds[wave * 16 * PSTRIDE];
        #pragma unroll
        for (int r = 0; r < 4; ++r) {
            int row = 4 * g + r;
            pw[row * PSTRIDE + r16]      = f2bf(p0[r]);
            pw[row * PSTRIDE + 16 + r16] = f2bf(p1[r]);
        }
        bf16x8 pf = *(const bf16x8*)&pw[r16 * PSTRIDE + 8 * g];

        // ---- rescale O, then O += P V
        #pragma unroll
        for (int dt = 0; dt < 8; ++dt) {
            #pragma unroll
            for (int r = 0; r < 4; ++r) o_acc[dt][r] *= alpha[r];
        }
        #pragma unroll
        for (int dt = 0; dt < 8; ++dt) {
            bf16x8 vf = *(const bf16x8*)&vt_lds[(16 * dt + r16) * VTSTRIDE + 8 * g];
            o_acc[dt] = __builtin_amdgcn_mfma_f32_16x16x32_bf16(pf, vf, o_acc[dt], 0, 0, 0);
        }
    }

    // ---- epilogue: O / l, write fp32
    #pragma unroll
    for (int r = 0; r < 4; ++r) {
        float inv = 1.0f / l_run[r];
        int row = qb * QBLK + wave * 16 + 4 * g + r;
        float* op = Oh + (size_t)row * DD + r16;
        #pragma unroll
        for (int dt = 0; dt < 8; ++dt)
            op[16 * dt] = o_acc[dt][r] * inv;
    }
}

extern "C" void kernel_launch(void* const* d_in, const int* in_sizes, int n_in,
                              void* d_out, int out_size, void* d_ws, size_t ws_size,
                              hipStream_t stream) {
    const float* q = (const float*)d_in[0];
    const float* k = (const float*)d_in[1];
    const float* v = (const float*)d_in[2];
    float* o = (float*)d_out;
    dim3 grid(LQ_N / QBLK, NHEADS);
    attn_fwd_kernel<<<grid, dim3(256), 0, stream>>>(q, k, v, o);
}

// Round 2
// 176.293 us; speedup vs baseline: 3.8278x; 3.8278x over previous
//
#include <hip/hip_runtime.h>
#include <hip/hip_bf16.h>
#include <cstdint>

// Problem constants (B=2, H=16 -> 32 heads)
#define LQ_N   2048
#define LK_N   2048
#define DD     128
#define NHEADS 32
#define QBLK   64
#define KVBLK  64
#define NKV    (LK_N / KVBLK)      // 32 kv tiles
#define SCALE  0.08838834764831845f   // 1/sqrt(128)

// ws layout: [K bf16 swizzled tiles][V^T bf16 swizzled tiles]
#define KTILE_BYTES (KVBLK * DD * 2)                 // 16 KiB per tile
#define WS_K_BYTES  ((size_t)NHEADS * NKV * KTILE_BYTES)   // 16 MiB
#define WS_NEED     (2 * WS_K_BYTES)                 // 32 MiB

#define PSTR 72   // P lds row stride (144 B: 16B-aligned, bank stride 4)

typedef __attribute__((ext_vector_type(8))) short bf16x8;
typedef __attribute__((ext_vector_type(4))) float f32x4;

__device__ inline unsigned short f2bf(float f) {
    union { float f; unsigned u; } x; x.f = f;
    unsigned r = (x.u + 0x7fffu + ((x.u >> 16) & 1u)) >> 16;  // RNE
    return (unsigned short)r;
}

// ---------------- pre-pass A: K fp32 -> bf16*SCALE, tile-major, XOR-swizzled
__global__ __launch_bounds__(256, 2)
void prep_k_kernel(const float* __restrict__ K, char* __restrict__ ws)
{
    const int tid  = threadIdx.x;
    const int kvt  = blockIdx.x;   // 0..31
    const int head = blockIdx.y;   // 0..31
    const float* Kh = K + ((size_t)head * LK_N + (size_t)kvt * KVBLK) * DD;
    char* dst = ws + ((size_t)head * NKV + kvt) * KTILE_BYTES;
    #pragma unroll
    for (int i = 0; i < 4; ++i) {
        int c = tid + 256 * i;          // 16B chunk id, 1024 per tile
        int row  = c >> 4;              // 0..63 (kv row)
        int col8 = c & 15;              // 8-elem group along D
        const float* src = Kh + (size_t)row * DD + col8 * 8;
        float4 a = *(const float4*)src;
        float4 b = *(const float4*)(src + 4);
        bf16x8 t;
        t[0] = (short)f2bf(a.x * SCALE); t[1] = (short)f2bf(a.y * SCALE);
        t[2] = (short)f2bf(a.z * SCALE); t[3] = (short)f2bf(a.w * SCALE);
        t[4] = (short)f2bf(b.x * SCALE); t[5] = (short)f2bf(b.y * SCALE);
        t[6] = (short)f2bf(b.z * SCALE); t[7] = (short)f2bf(b.w * SCALE);
        *(bf16x8*)(dst + row * 256 + ((col8 * 16) ^ ((row & 7) << 4))) = t;
    }
}

// ---------------- pre-pass B: V fp32 -> V^T bf16, tile-major, XOR-swizzled
__global__ __launch_bounds__(256, 2)
void prep_vt_kernel(const float* __restrict__ V, char* __restrict__ ws)
{
    __shared__ unsigned short vt[DD * PSTR];   // [128 d][64 kv] (+pad)
    const int tid  = threadIdx.x;
    const int kvt  = blockIdx.x;
    const int head = blockIdx.y;
    const float* Vh = V + ((size_t)head * LK_N + (size_t)kvt * KVBLK) * DD;
    // load V tile coalesced, transpose into LDS (one-time cost)
    #pragma unroll
    for (int i = 0; i < 8; ++i) {
        int f = tid + 256 * i;          // float4 id, 2048 per tile
        int r  = f >> 5;                // kv row 0..63
        int c4 = f & 31;                // float4 along D
        float4 x = *(const float4*)(Vh + (size_t)r * DD + c4 * 4);
        vt[(c4 * 4 + 0) * PSTR + r] = f2bf(x.x);
        vt[(c4 * 4 + 1) * PSTR + r] = f2bf(x.y);
        vt[(c4 * 4 + 2) * PSTR + r] = f2bf(x.z);
        vt[(c4 * 4 + 3) * PSTR + r] = f2bf(x.w);
    }
    __syncthreads();
    char* dst = ws + WS_K_BYTES + ((size_t)head * NKV + kvt) * KTILE_BYTES;
    #pragma unroll
    for (int i = 0; i < 4; ++i) {
        int c = tid + 256 * i;          // 16B chunk id
        int d   = c >> 3;               // 0..127
        int kv8 = c & 7;                // 8-elem group along kv
        bf16x8 t = *(const bf16x8*)&vt[d * PSTR + kv8 * 8];   // 16B aligned (144d+16k)
        *(bf16x8*)(dst + d * 128 + ((kv8 * 16) ^ ((d & 7) << 4))) = t;
    }
}

// ---------------- main attention kernel (bf16 tiles from ws)
__global__ __launch_bounds__(256, 2)
void attn_main_kernel(const float* __restrict__ Q, const char* __restrict__ kws,
                      const char* __restrict__ vws, float* __restrict__ O)
{
    __shared__ unsigned short kt_lds[KVBLK * DD];     // 16 KiB, swizzled image
    __shared__ unsigned short vt_lds[DD * KVBLK];     // 16 KiB, swizzled image
    __shared__ unsigned short p_lds[4 * 16 * PSTR];   // per-wave P tiles

    const int tid  = threadIdx.x;
    const int lane = tid & 63;
    const int wave = tid >> 6;
    const int head = blockIdx.y;
    const int qb   = blockIdx.x;
    const int r16  = lane & 15;
    const int g    = lane >> 4;

    const float* Qh = Q + (size_t)head * LQ_N * DD;
    float*       Oh = O + (size_t)head * LQ_N * DD;
    const char*  kt_g = kws + (size_t)head * NKV * KTILE_BYTES;
    const char*  vt_g = vws + (size_t)head * NKV * KTILE_BYTES;

    // Q fragments (A-frag: lane holds Q[r16][32*kt + 8*g + j])
    const int qrow = qb * QBLK + wave * 16 + r16;
    bf16x8 qf[4];
    {
        const float* qp = Qh + (size_t)qrow * DD + 8 * g;
        #pragma unroll
        for (int kt = 0; kt < 4; ++kt) {
            float4 a = *(const float4*)(qp + 32 * kt);
            float4 b = *(const float4*)(qp + 32 * kt + 4);
            bf16x8 t;
            t[0] = (short)f2bf(a.x); t[1] = (short)f2bf(a.y);
            t[2] = (short)f2bf(a.z); t[3] = (short)f2bf(a.w);
            t[4] = (short)f2bf(b.x); t[5] = (short)f2bf(b.y);
            t[6] = (short)f2bf(b.z); t[7] = (short)f2bf(b.w);
            qf[kt] = t;
        }
    }

    f32x4 o_acc[8];
    #pragma unroll
    for (int dt = 0; dt < 8; ++dt) o_acc[dt] = (f32x4){0.f, 0.f, 0.f, 0.f};
    float m_run[4], l_run[4];
    #pragma unroll
    for (int r = 0; r < 4; ++r) { m_run[r] = -1e30f; l_run[r] = 0.f; }

    // prologue: prefetch tile 0 into regs (16B chunks)
    const bf16x8* kg = (const bf16x8*)kt_g;
    const bf16x8* vg = (const bf16x8*)vt_g;
    bf16x8 skreg[4], svreg[4];
    #pragma unroll
    for (int i = 0; i < 4; ++i) { skreg[i] = kg[tid + 256 * i]; svreg[i] = vg[tid + 256 * i]; }

    for (int t = 0; t < NKV; ++t) {
        __syncthreads();   // all waves done reading previous tile
        #pragma unroll
        for (int i = 0; i < 4; ++i) {
            *(bf16x8*)&kt_lds[(tid + 256 * i) * 8] = skreg[i];
            *(bf16x8*)&vt_lds[(tid + 256 * i) * 8] = svreg[i];
        }
        __syncthreads();   // tile visible to all waves

        // prefetch next tile (in flight during compute; drained at next barrier)
        if (t + 1 < NKV) {
            int base = (t + 1) * (KTILE_BYTES / 16);
            #pragma unroll
            for (int i = 0; i < 4; ++i) {
                skreg[i] = kg[base + tid + 256 * i];
                svreg[i] = vg[base + tid + 256 * i];
            }
        }

        // ---- S = Q K^T : wave's 16 q-rows x 64 kv cols (4 n-tiles)
        f32x4 s[4];
        #pragma unroll
        for (int nn = 0; nn < 4; ++nn) s[nn] = (f32x4){0.f, 0.f, 0.f, 0.f};
        #pragma unroll
        for (int kt = 0; kt < 4; ++kt) {
            #pragma unroll
            for (int nn = 0; nn < 4; ++nn) {
                int row = nn * 16 + r16;
                bf16x8 kf = *(const bf16x8*)((const char*)kt_lds + row * 256 +
                                             ((64 * kt + 16 * g) ^ ((row & 7) << 4)));
                s[nn] = __builtin_amdgcn_mfma_f32_16x16x32_bf16(qf[kt], kf, s[nn], 0, 0, 0);
            }
        }

        // ---- online softmax (q-row 4g+r, kv col nn*16 + r16)
        float alpha[4];
        f32x4 p[4];
        #pragma unroll
        for (int r = 0; r < 4; ++r) {
            float tmax = fmaxf(fmaxf(s[0][r], s[1][r]), fmaxf(s[2][r], s[3][r]));
            tmax = fmaxf(tmax, __shfl_xor(tmax, 1));
            tmax = fmaxf(tmax, __shfl_xor(tmax, 2));
            tmax = fmaxf(tmax, __shfl_xor(tmax, 4));
            tmax = fmaxf(tmax, __shfl_xor(tmax, 8));
            float mn = fmaxf(m_run[r], tmax);
            alpha[r] = __expf(m_run[r] - mn);
            m_run[r] = mn;
            float sum = 0.f;
            #pragma unroll
            for (int nn = 0; nn < 4; ++nn) { p[nn][r] = __expf(s[nn][r] - mn); sum += p[nn][r]; }
            sum += __shfl_xor(sum, 1);
            sum += __shfl_xor(sum, 2);
            sum += __shfl_xor(sum, 4);
            sum += __shfl_xor(sum, 8);
            l_run[r] = l_run[r] * alpha[r] + sum;
        }

        // ---- P -> per-wave LDS tile, read back as A-fragments
        unsigned short* pw = &p_lds[wave * 16 * PSTR];
        #pragma unroll
        for (int r = 0; r < 4; ++r) {
            int row = 4 * g + r;
            #pragma unroll
            for (int nn = 0; nn < 4; ++nn)
                pw[row * PSTR + nn * 16 + r16] = f2bf(p[nn][r]);
        }
        bf16x8 pf0 = *(const bf16x8*)((const char*)pw + r16 * 144 + 16 * g);
        bf16x8 pf1 = *(const bf16x8*)((const char*)pw + r16 * 144 + 64 + 16 * g);

        // ---- rescale O, then O += P V
        #pragma unroll
        for (int dt = 0; dt < 8; ++dt) {
            #pragma unroll
            for (int r = 0; r < 4; ++r) o_acc[dt][r] *= alpha[r];
        }
        #pragma unroll
        for (int dt = 0; dt < 8; ++dt) {
            int d0 = dt * 16 + r16;
            bf16x8 vf0 = *(const bf16x8*)((const char*)vt_lds + d0 * 128 +
                                          ((16 * g) ^ ((d0 & 7) << 4)));
            bf16x8 vf1 = *(const bf16x8*)((const char*)vt_lds + d0 * 128 +
                                          ((64 + 16 * g) ^ ((d0 & 7) << 4)));
            o_acc[dt] = __builtin_amdgcn_mfma_f32_16x16x32_bf16(pf0, vf0, o_acc[dt], 0, 0, 0);
            o_acc[dt] = __builtin_amdgcn_mfma_f32_16x16x32_bf16(pf1, vf1, o_acc[dt], 0, 0, 0);
        }
    }

    // ---- epilogue
    #pragma unroll
    for (int r = 0; r < 4; ++r) {
        float inv = 1.0f / l_run[r];
        int row = qb * QBLK + wave * 16 + 4 * g + r;
        float* op = Oh + (size_t)row * DD + r16;
        #pragma unroll
        for (int dt = 0; dt < 8; ++dt)
            op[16 * dt] = o_acc[dt][r] * inv;
    }
}

// ================= fallback (round-1 kernel, passes, used if ws too small) ==
#define KSTRIDE  136
#define VTSTRIDE 40
#define FKV 32

__global__ __launch_bounds__(256, 2)
void attn_fwd_fallback(const float* __restrict__ Q, const float* __restrict__ K,
                       const float* __restrict__ V, float* __restrict__ O)
{
    __shared__ unsigned short k_lds[FKV * KSTRIDE];
    __shared__ unsigned short vt_lds[DD * VTSTRIDE];
    __shared__ unsigned short p_lds2[4 * 16 * VTSTRIDE];

    const int tid  = threadIdx.x;
    const int lane = tid & 63;
    const int wave = tid >> 6;
    const int head = blockIdx.y;
    const int qb   = blockIdx.x;

    const float* Qh = Q + (size_t)head * LQ_N * DD;
    const float* Kh = K + (size_t)head * LK_N * DD;
    const float* Vh = V + (size_t)head * LK_N * DD;
    float*       Oh = O + (size_t)head * LQ_N * DD;

    const int r16 = lane & 15;
    const int g   = lane >> 4;

    const int qrow = qb * QBLK + wave * 16 + r16;
    bf16x8 qf[4];
    {
        const float* qp = Qh + (size_t)qrow * DD + 8 * g;
        #pragma unroll
        for (int kt = 0; kt < 4; ++kt) {
            float4 a = *(const float4*)(qp + 32 * kt);
            float4 b = *(const float4*)(qp + 32 * kt + 4);
            bf16x8 t;
            t[0] = (short)f2bf(a.x * SCALE); t[1] = (short)f2bf(a.y * SCALE);
            t[2] = (short)f2bf(a.z * SCALE); t[3] = (short)f2bf(a.w * SCALE);
            t[4] = (short)f2bf(b.x * SCALE); t[5] = (short)f2bf(b.y * SCALE);
            t[6] = (short)f2bf(b.z * SCALE); t[7] = (short)f2bf(b.w * SCALE);
            qf[kt] = t;
        }
    }

    f32x4 o_acc[8];
    #pragma unroll
    for (int dt = 0; dt < 8; ++dt) o_acc[dt] = (f32x4){0.f, 0.f, 0.f, 0.f};
    float m_run[4], l_run[4];
    #pragma unroll
    for (int r = 0; r < 4; ++r) { m_run[r] = -1e30f; l_run[r] = 0.f; }

    for (int kv = 0; kv < LK_N / FKV; ++kv) {
        const float* Kt = Kh + (size_t)kv * FKV * DD;
        const float* Vt = Vh + (size_t)kv * FKV * DD;
        __syncthreads();
        #pragma unroll
        for (int i = 0; i < 4; ++i) {
            int f = tid + 256 * i;
            int row = f >> 5, colf = f & 31;
            float4 x = *(const float4*)(Kt + (size_t)row * DD + colf * 4);
            ushort4 pk;
            pk.x = f2bf(x.x); pk.y = f2bf(x.y); pk.z = f2bf(x.z); pk.w = f2bf(x.w);
            *(ushort4*)(&k_lds[row * KSTRIDE + colf * 4]) = pk;
        }
        #pragma unroll
        for (int i = 0; i < 4; ++i) {
            int f = tid + 256 * i;
            int row = f >> 5, colf = f & 31;
            float4 x = *(const float4*)(Vt + (size_t)row * DD + colf * 4);
            vt_lds[(colf * 4 + 0) * VTSTRIDE + row] = f2bf(x.x);
            vt_lds[(colf * 4 + 1) * VTSTRIDE + row] = f2bf(x.y);
            vt_lds[(colf * 4 + 2) * VTSTRIDE + row] = f2bf(x.z);
            vt_lds[(colf * 4 + 3) * VTSTRIDE + row] = f2bf(x.w);
        }
        __syncthreads();

        f32x4 s0 = (f32x4){0.f,0.f,0.f,0.f};
        f32x4 s1 = (f32x4){0.f,0.f,0.f,0.f};
        #pragma unroll
        for (int kt = 0; kt < 4; ++kt) {
            bf16x8 kf0 = *(const bf16x8*)&k_lds[(r16)      * KSTRIDE + 32 * kt + 8 * g];
            bf16x8 kf1 = *(const bf16x8*)&k_lds[(16 + r16) * KSTRIDE + 32 * kt + 8 * g];
            s0 = __builtin_amdgcn_mfma_f32_16x16x32_bf16(qf[kt], kf0, s0, 0, 0, 0);
            s1 = __builtin_amdgcn_mfma_f32_16x16x32_bf16(qf[kt], kf1, s1, 0, 0, 0);
        }

        float alpha[4];
        f32x4 p0, p1;
        #pragma unroll
        for (int r = 0; r < 4; ++r) {
            float t = fmaxf(s0[r], s1[r]);
            t = fmaxf(t, __shfl_xor(t, 1));
            t = fmaxf(t, __shfl_xor(t, 2));
            t = fmaxf(t, __shfl_xor(t, 4));
            t = fmaxf(t, __shfl_xor(t, 8));
            float mn = fmaxf(m_run[r], t);
            alpha[r] = __expf(m_run[r] - mn);
            m_run[r] = mn;
            p0[r] = __expf(s0[r] - mn);
            p1[r] = __expf(s1[r] - mn);
            float su = p0[r] + p1[r];
            su += __shfl_xor(su, 1);
            su += __shfl_xor(su, 2);
            su += __shfl_xor(su, 4);
            su += __shfl_xor(su, 8);
            l_run[r] = l_run[r] * alpha[r] + su;
        }

        unsigned short* pw = &p_lds2[wave * 16 * VTSTRIDE];
        #pragma unroll
        for (int r = 0; r < 4; ++r) {
            int row = 4 * g + r;
            pw[row * VTSTRIDE + r16]      = f2bf(p0[r]);
            pw[row * VTSTRIDE + 16 + r16] = f2bf(p1[r]);
        }
        bf16x8 pf = *(const bf16x8*)&pw[r16 * VTSTRIDE + 8 * g];

        #pragma unroll
        for (int dt = 0; dt < 8; ++dt) {
            #pragma unroll
            for (int r = 0; r < 4; ++r) o_acc[dt][r] *= alpha[r];
        }
        #pragma unroll
        for (int dt = 0; dt < 8; ++dt) {
            bf16x8 vf = *(const bf16x8*)&vt_lds[(16 * dt + r16) * VTSTRIDE + 8 * g];
            o_acc[dt] = __builtin_amdgcn_mfma_f32_16x16x32_bf16(pf, vf, o_acc[dt], 0, 0, 0);
        }
    }

    #pragma unroll
    for (int r = 0; r < 4; ++r) {
        float inv = 1.0f / l_run[r];
        int row = qb * QBLK + wave * 16 + 4 * g + r;
        float* op = Oh + (size_t)row * DD + r16;
        #pragma unroll
        for (int dt = 0; dt < 8; ++dt)
            op[16 * dt] = o_acc[dt][r] * inv;
    }
}

extern "C" void kernel_launch(void* const* d_in, const int* in_sizes, int n_in,
                              void* d_out, int out_size, void* d_ws, size_t ws_size,
                              hipStream_t stream) {
    const float* q = (const float*)d_in[0];
    const float* k = (const float*)d_in[1];
    const float* v = (const float*)d_in[2];
    float* o = (float*)d_out;

    if (ws_size >= WS_NEED) {
        char* ws = (char*)d_ws;
        prep_k_kernel <<<dim3(NKV, NHEADS), 256, 0, stream>>>(k, ws);
        prep_vt_kernel<<<dim3(NKV, NHEADS), 256, 0, stream>>>(v, ws);
        attn_main_kernel<<<dim3(LQ_N / QBLK, NHEADS), 256, 0, stream>>>(
            q, ws, ws + WS_K_BYTES, o);
    } else {
        attn_fwd_fallback<<<dim3(LQ_N / QBLK, NHEADS), 256, 0, stream>>>(q, k, v, o);
    }
}

// Round 3
// 137.405 us; speedup vs baseline: 4.9112x; 1.2830x over previous
//
#include <hip/hip_runtime.h>
#include <hip/hip_bf16.h>
#include <cstdint>

// Problem constants (B=2, H=16 -> 32 heads)
#define LQ_N   2048
#define LK_N   2048
#define DD     128
#define NHEADS 32
#define QBLK   128               // q rows per block (4 waves x 32 rows)
#define KVBLK  64
#define NKV    (LK_N / KVBLK)    // 32 kv tiles
#define NQB    (LQ_N / QBLK)     // 16 q blocks
#define SCALE  0.08838834764831845f            // 1/sqrt(128)
#define SCALE2 0.1275525003267101f             // SCALE * log2(e)

// ws layout: [K bf16 swizzled tiles][V^T bf16 swizzled tiles]
#define KTILE_BYTES (KVBLK * DD * 2)                        // 16 KiB per tile
#define WS_K_BYTES  ((size_t)NHEADS * NKV * KTILE_BYTES)    // 16 MiB
#define WS_NEED     (2 * WS_K_BYTES)                        // 32 MiB

#define PSTR 72   // P lds row stride in elements (144 B)

typedef __attribute__((ext_vector_type(8))) short bf16x8;
typedef __attribute__((ext_vector_type(4))) float f32x4;

#if __has_builtin(__builtin_amdgcn_exp2f)
#define EXP2F __builtin_amdgcn_exp2f
#else
#define EXP2F exp2f
#endif

__device__ inline unsigned short f2bf(float f) {
    union { float f; unsigned u; } x; x.f = f;
    unsigned r = (x.u + 0x7fffu + ((x.u >> 16) & 1u)) >> 16;  // RNE
    return (unsigned short)r;
}

// ---------------- pre-pass A: K fp32 -> bf16*SCALE2, tile-major, XOR-swizzled
__global__ __launch_bounds__(256, 2)
void prep_k_kernel(const float* __restrict__ K, char* __restrict__ ws)
{
    const int tid  = threadIdx.x;
    const int kvt  = blockIdx.x;
    const int head = blockIdx.y;
    const float* Kh = K + ((size_t)head * LK_N + (size_t)kvt * KVBLK) * DD;
    char* dst = ws + ((size_t)head * NKV + kvt) * KTILE_BYTES;
    #pragma unroll
    for (int i = 0; i < 4; ++i) {
        int c = tid + 256 * i;          // 16B chunk id, 1024 per tile
        int row  = c >> 4;              // 0..63 (kv row)
        int col8 = c & 15;              // 8-elem group along D
        const float* src = Kh + (size_t)row * DD + col8 * 8;
        float4 a = *(const float4*)src;
        float4 b = *(const float4*)(src + 4);
        bf16x8 t;
        t[0] = (short)f2bf(a.x * SCALE2); t[1] = (short)f2bf(a.y * SCALE2);
        t[2] = (short)f2bf(a.z * SCALE2); t[3] = (short)f2bf(a.w * SCALE2);
        t[4] = (short)f2bf(b.x * SCALE2); t[5] = (short)f2bf(b.y * SCALE2);
        t[6] = (short)f2bf(b.z * SCALE2); t[7] = (short)f2bf(b.w * SCALE2);
        *(bf16x8*)(dst + row * 256 + ((col8 * 16) ^ ((row & 7) << 4))) = t;
    }
}

// ---------------- pre-pass B: V fp32 -> V^T bf16, tile-major, XOR-swizzled
__global__ __launch_bounds__(256, 2)
void prep_vt_kernel(const float* __restrict__ V, char* __restrict__ ws)
{
    __shared__ unsigned short vt[DD * PSTR];
    const int tid  = threadIdx.x;
    const int kvt  = blockIdx.x;
    const int head = blockIdx.y;
    const float* Vh = V + ((size_t)head * LK_N + (size_t)kvt * KVBLK) * DD;
    #pragma unroll
    for (int i = 0; i < 8; ++i) {
        int f = tid + 256 * i;          // float4 id, 2048 per tile
        int r  = f >> 5;                // kv row 0..63
        int c4 = f & 31;                // float4 along D
        float4 x = *(const float4*)(Vh + (size_t)r * DD + c4 * 4);
        vt[(c4 * 4 + 0) * PSTR + r] = f2bf(x.x);
        vt[(c4 * 4 + 1) * PSTR + r] = f2bf(x.y);
        vt[(c4 * 4 + 2) * PSTR + r] = f2bf(x.z);
        vt[(c4 * 4 + 3) * PSTR + r] = f2bf(x.w);
    }
    __syncthreads();
    char* dst = ws + WS_K_BYTES + ((size_t)head * NKV + kvt) * KTILE_BYTES;
    #pragma unroll
    for (int i = 0; i < 4; ++i) {
        int c = tid + 256 * i;          // 16B chunk id
        int d   = c >> 3;               // 0..127
        int kv8 = c & 7;                // 8-elem group along kv
        bf16x8 t = *(const bf16x8*)&vt[d * PSTR + kv8 * 8];
        *(bf16x8*)(dst + d * 128 + ((kv8 * 16) ^ ((d & 7) << 4))) = t;
    }
}

// ---------------- main attention kernel (bf16 tiles from ws)
__global__ __launch_bounds__(256, 2)
void attn_main_kernel(const float* __restrict__ Q, const char* __restrict__ kws,
                      const char* __restrict__ vws, float* __restrict__ O)
{
    __shared__ unsigned short kt_lds[KVBLK * DD];      // 16 KiB, swizzled image
    __shared__ unsigned short vt_lds[DD * KVBLK];      // 16 KiB, swizzled image
    __shared__ unsigned short p_lds[4 * 32 * PSTR];    // per-wave P tiles [32][72]

    const int tid  = threadIdx.x;
    const int lane = tid & 63;
    const int wave = tid >> 6;
    const int r16  = lane & 15;
    const int g    = lane >> 4;

    // XCD-aware bijective swizzle: 512 blocks, 8 XCDs, 64-block chunks
    const int bid  = blockIdx.x;
    const int sid  = (bid & 7) * (NQB * NHEADS / 8) + (bid >> 3);
    const int head = sid >> 4;       // /NQB
    const int qb   = sid & 15;       // %NQB

    const float* Qh = Q + (size_t)head * LQ_N * DD;
    float*       Oh = O + (size_t)head * LQ_N * DD;
    const char*  kt_g = kws + (size_t)head * NKV * KTILE_BYTES;
    const char*  vt_g = vws + (size_t)head * NKV * KTILE_BYTES;

    // Q fragments: lane holds Q[qrow = base+qt*16+r16][32*kt + 8*g + j]
    bf16x8 qf[2][4];
    #pragma unroll
    for (int qt = 0; qt < 2; ++qt) {
        const int qrow = qb * QBLK + wave * 32 + qt * 16 + r16;
        const float* qp = Qh + (size_t)qrow * DD + 8 * g;
        #pragma unroll
        for (int kt = 0; kt < 4; ++kt) {
            float4 a = *(const float4*)(qp + 32 * kt);
            float4 b = *(const float4*)(qp + 32 * kt + 4);
            bf16x8 t;
            t[0] = (short)f2bf(a.x); t[1] = (short)f2bf(a.y);
            t[2] = (short)f2bf(a.z); t[3] = (short)f2bf(a.w);
            t[4] = (short)f2bf(b.x); t[5] = (short)f2bf(b.y);
            t[6] = (short)f2bf(b.z); t[7] = (short)f2bf(b.w);
            qf[qt][kt] = t;
        }
    }

    f32x4 o_acc[2][8];
    #pragma unroll
    for (int qt = 0; qt < 2; ++qt)
        #pragma unroll
        for (int dt = 0; dt < 8; ++dt) o_acc[qt][dt] = (f32x4){0.f, 0.f, 0.f, 0.f};
    float m_run[2] = {-1e30f, -1e30f};
    float l_run[2] = {0.f, 0.f};

    // prologue: prefetch tile 0 into regs (16B chunks)
    const bf16x8* kg = (const bf16x8*)kt_g;
    const bf16x8* vg = (const bf16x8*)vt_g;
    bf16x8 skreg[4], svreg[4];
    #pragma unroll
    for (int i = 0; i < 4; ++i) { skreg[i] = kg[tid + 256 * i]; svreg[i] = vg[tid + 256 * i]; }

    unsigned short* pw = &p_lds[wave * 32 * PSTR];
    const char* pwb = (const char*)pw;

    for (int t = 0; t < NKV; ++t) {
        __syncthreads();
        #pragma unroll
        for (int i = 0; i < 4; ++i) {
            *(bf16x8*)&kt_lds[(tid + 256 * i) * 8] = skreg[i];
            *(bf16x8*)&vt_lds[(tid + 256 * i) * 8] = svreg[i];
        }
        __syncthreads();

        if (t + 1 < NKV) {
            int base = (t + 1) * (KTILE_BYTES / 16);
            #pragma unroll
            for (int i = 0; i < 4; ++i) {
                skreg[i] = kg[base + tid + 256 * i];
                svreg[i] = vg[base + tid + 256 * i];
            }
        }

        // ---- S^T = K Q^T : lane holds S[kv = 16nn+4g+r][q = qt*16 + r16]
        f32x4 s[2][4];
        #pragma unroll
        for (int qt = 0; qt < 2; ++qt)
            #pragma unroll
            for (int nn = 0; nn < 4; ++nn) s[qt][nn] = (f32x4){0.f, 0.f, 0.f, 0.f};
        __builtin_amdgcn_s_setprio(1);
        #pragma unroll
        for (int kt = 0; kt < 4; ++kt) {
            bf16x8 kf[4];
            #pragma unroll
            for (int nn = 0; nn < 4; ++nn) {
                int row = nn * 16 + r16;
                kf[nn] = *(const bf16x8*)((const char*)kt_lds + row * 256 +
                                          ((64 * kt + 16 * g) ^ ((row & 7) << 4)));
            }
            #pragma unroll
            for (int qt = 0; qt < 2; ++qt)
                #pragma unroll
                for (int nn = 0; nn < 4; ++nn)
                    s[qt][nn] = __builtin_amdgcn_mfma_f32_16x16x32_bf16(kf[nn], qf[qt][kt], s[qt][nn], 0, 0, 0);
        }
        __builtin_amdgcn_s_setprio(0);

        // ---- online softmax, lane-local over 16 kv values per qt
        float alpha[2];
        #pragma unroll
        for (int qt = 0; qt < 2; ++qt) {
            float pm = fmaxf(fmaxf(fmaxf(s[qt][0][0], s[qt][0][1]), fmaxf(s[qt][0][2], s[qt][0][3])),
                             fmaxf(fmaxf(s[qt][1][0], s[qt][1][1]), fmaxf(s[qt][1][2], s[qt][1][3])));
            float pm2 = fmaxf(fmaxf(fmaxf(s[qt][2][0], s[qt][2][1]), fmaxf(s[qt][2][2], s[qt][2][3])),
                              fmaxf(fmaxf(s[qt][3][0], s[qt][3][1]), fmaxf(s[qt][3][2], s[qt][3][3])));
            pm = fmaxf(pm, pm2);
            pm = fmaxf(pm, __shfl_xor(pm, 16));
            pm = fmaxf(pm, __shfl_xor(pm, 32));
            float mn = fmaxf(m_run[qt], pm);
            float al = EXP2F(m_run[qt] - mn);
            m_run[qt] = mn;
            float sum = 0.f;
            #pragma unroll
            for (int nn = 0; nn < 4; ++nn)
                #pragma unroll
                for (int r = 0; r < 4; ++r) {
                    float p = EXP2F(s[qt][nn][r] - mn);
                    s[qt][nn][r] = p;
                    sum += p;
                }
            sum += __shfl_xor(sum, 16);
            sum += __shfl_xor(sum, 32);
            l_run[qt] = l_run[qt] * al + sum;
            alpha[qt] = al;
        }

        // ---- P^T regs -> per-wave LDS tile (swizzled), read back as A-frags
        #pragma unroll
        for (int qt = 0; qt < 2; ++qt) {
            int rowbase = (qt * 16 + r16) * 144;
            int sw = (r16 & 7) << 4;
            #pragma unroll
            for (int nn = 0; nn < 4; ++nn)
                #pragma unroll
                for (int r = 0; r < 4; ++r) {
                    int kv = 16 * nn + 4 * g + r;
                    int byte = rowbase + (((kv >> 3) << 4) ^ sw) + (kv & 7) * 2;
                    *(unsigned short*)((char*)pw + byte) = f2bf(s[qt][nn][r]);
                }
        }
        bf16x8 pf00 = *(const bf16x8*)(pwb + (0 * 16 + r16) * 144 + (((g    ) << 4) ^ ((r16 & 7) << 4)));
        bf16x8 pf01 = *(const bf16x8*)(pwb + (0 * 16 + r16) * 144 + (((4 + g) << 4) ^ ((r16 & 7) << 4)));
        bf16x8 pf10 = *(const bf16x8*)(pwb + (1 * 16 + r16) * 144 + (((g    ) << 4) ^ ((r16 & 7) << 4)));
        bf16x8 pf11 = *(const bf16x8*)(pwb + (1 * 16 + r16) * 144 + (((4 + g) << 4) ^ ((r16 & 7) << 4)));

        // ---- broadcast alpha to accumulator-row owners, rescale O
        float ab[2][4];
        #pragma unroll
        for (int qt = 0; qt < 2; ++qt)
            #pragma unroll
            for (int r = 0; r < 4; ++r)
                ab[qt][r] = __shfl(alpha[qt], 4 * g + r);
        #pragma unroll
        for (int qt = 0; qt < 2; ++qt)
            #pragma unroll
            for (int dt = 0; dt < 8; ++dt)
                #pragma unroll
                for (int r = 0; r < 4; ++r) o_acc[qt][dt][r] *= ab[qt][r];

        // ---- O += P V
        __builtin_amdgcn_s_setprio(1);
        #pragma unroll
        for (int dt = 0; dt < 8; ++dt) {
            int d0 = dt * 16 + r16;
            bf16x8 vf0 = *(const bf16x8*)((const char*)vt_lds + d0 * 128 +
                                          ((16 * g) ^ ((d0 & 7) << 4)));
            bf16x8 vf1 = *(const bf16x8*)((const char*)vt_lds + d0 * 128 +
                                          ((64 + 16 * g) ^ ((d0 & 7) << 4)));
            o_acc[0][dt] = __builtin_amdgcn_mfma_f32_16x16x32_bf16(pf00, vf0, o_acc[0][dt], 0, 0, 0);
            o_acc[0][dt] = __builtin_amdgcn_mfma_f32_16x16x32_bf16(pf01, vf1, o_acc[0][dt], 0, 0, 0);
            o_acc[1][dt] = __builtin_amdgcn_mfma_f32_16x16x32_bf16(pf10, vf0, o_acc[1][dt], 0, 0, 0);
            o_acc[1][dt] = __builtin_amdgcn_mfma_f32_16x16x32_bf16(pf11, vf1, o_acc[1][dt], 0, 0, 0);
        }
        __builtin_amdgcn_s_setprio(0);
    }

    // ---- epilogue: O / l, write fp32
    #pragma unroll
    for (int qt = 0; qt < 2; ++qt)
        #pragma unroll
        for (int r = 0; r < 4; ++r) {
            float lb = __shfl(l_run[qt], 4 * g + r);
            float inv = 1.0f / lb;
            int row = qb * QBLK + wave * 32 + qt * 16 + 4 * g + r;
            float* op = Oh + (size_t)row * DD + r16;
            #pragma unroll
            for (int dt = 0; dt < 8; ++dt)
                op[16 * dt] = o_acc[qt][dt][r] * inv;
        }
}

// ================= fallback (round-1 kernel, used if ws too small) ==========
#define KSTRIDE  136
#define VTSTRIDE 40
#define FKV 32

__global__ __launch_bounds__(256, 2)
void attn_fwd_fallback(const float* __restrict__ Q, const float* __restrict__ K,
                       const float* __restrict__ V, float* __restrict__ O)
{
    __shared__ unsigned short k_lds[FKV * KSTRIDE];
    __shared__ unsigned short vt_lds[DD * VTSTRIDE];
    __shared__ unsigned short p_lds2[4 * 16 * VTSTRIDE];

    const int tid  = threadIdx.x;
    const int lane = tid & 63;
    const int wave = tid >> 6;
    const int head = blockIdx.y;
    const int qb   = blockIdx.x;

    const float* Qh = Q + (size_t)head * LQ_N * DD;
    const float* Kh = K + (size_t)head * LK_N * DD;
    const float* Vh = V + (size_t)head * LK_N * DD;
    float*       Oh = O + (size_t)head * LQ_N * DD;

    const int r16 = lane & 15;
    const int g   = lane >> 4;

    const int qrow = qb * 64 + wave * 16 + r16;
    bf16x8 qf[4];
    {
        const float* qp = Qh + (size_t)qrow * DD + 8 * g;
        #pragma unroll
        for (int kt = 0; kt < 4; ++kt) {
            float4 a = *(const float4*)(qp + 32 * kt);
            float4 b = *(const float4*)(qp + 32 * kt + 4);
            bf16x8 t;
            t[0] = (short)f2bf(a.x * SCALE); t[1] = (short)f2bf(a.y * SCALE);
            t[2] = (short)f2bf(a.z * SCALE); t[3] = (short)f2bf(a.w * SCALE);
            t[4] = (short)f2bf(b.x * SCALE); t[5] = (short)f2bf(b.y * SCALE);
            t[6] = (short)f2bf(b.z * SCALE); t[7] = (short)f2bf(b.w * SCALE);
            qf[kt] = t;
        }
    }

    f32x4 o_acc[8];
    #pragma unroll
    for (int dt = 0; dt < 8; ++dt) o_acc[dt] = (f32x4){0.f, 0.f, 0.f, 0.f};
    float m_run[4], l_run[4];
    #pragma unroll
    for (int r = 0; r < 4; ++r) { m_run[r] = -1e30f; l_run[r] = 0.f; }

    for (int kv = 0; kv < LK_N / FKV; ++kv) {
        const float* Kt = Kh + (size_t)kv * FKV * DD;
        const float* Vt = Vh + (size_t)kv * FKV * DD;
        __syncthreads();
        #pragma unroll
        for (int i = 0; i < 4; ++i) {
            int f = tid + 256 * i;
            int row = f >> 5, colf = f & 31;
            float4 x = *(const float4*)(Kt + (size_t)row * DD + colf * 4);
            ushort4 pk;
            pk.x = f2bf(x.x); pk.y = f2bf(x.y); pk.z = f2bf(x.z); pk.w = f2bf(x.w);
            *(ushort4*)(&k_lds[row * KSTRIDE + colf * 4]) = pk;
        }
        #pragma unroll
        for (int i = 0; i < 4; ++i) {
            int f = tid + 256 * i;
            int row = f >> 5, colf = f & 31;
            float4 x = *(const float4*)(Vt + (size_t)row * DD + colf * 4);
            vt_lds[(colf * 4 + 0) * VTSTRIDE + row] = f2bf(x.x);
            vt_lds[(colf * 4 + 1) * VTSTRIDE + row] = f2bf(x.y);
            vt_lds[(colf * 4 + 2) * VTSTRIDE + row] = f2bf(x.z);
            vt_lds[(colf * 4 + 3) * VTSTRIDE + row] = f2bf(x.w);
        }
        __syncthreads();

        f32x4 s0 = (f32x4){0.f,0.f,0.f,0.f};
        f32x4 s1 = (f32x4){0.f,0.f,0.f,0.f};
        #pragma unroll
        for (int kt = 0; kt < 4; ++kt) {
            bf16x8 kf0 = *(const bf16x8*)&k_lds[(r16)      * KSTRIDE + 32 * kt + 8 * g];
            bf16x8 kf1 = *(const bf16x8*)&k_lds[(16 + r16) * KSTRIDE + 32 * kt + 8 * g];
            s0 = __builtin_amdgcn_mfma_f32_16x16x32_bf16(qf[kt], kf0, s0, 0, 0, 0);
            s1 = __builtin_amdgcn_mfma_f32_16x16x32_bf16(qf[kt], kf1, s1, 0, 0, 0);
        }

        float alpha[4];
        f32x4 p0, p1;
        #pragma unroll
        for (int r = 0; r < 4; ++r) {
            float t = fmaxf(s0[r], s1[r]);
            t = fmaxf(t, __shfl_xor(t, 1));
            t = fmaxf(t, __shfl_xor(t, 2));
            t = fmaxf(t, __shfl_xor(t, 4));
            t = fmaxf(t, __shfl_xor(t, 8));
            float mn = fmaxf(m_run[r], t);
            alpha[r] = __expf(m_run[r] - mn);
            m_run[r] = mn;
            p0[r] = __expf(s0[r] - mn);
            p1[r] = __expf(s1[r] - mn);
            float su = p0[r] + p1[r];
            su += __shfl_xor(su, 1);
            su += __shfl_xor(su, 2);
            su += __shfl_xor(su, 4);
            su += __shfl_xor(su, 8);
            l_run[r] = l_run[r] * alpha[r] + su;
        }

        unsigned short* pw = &p_lds2[wave * 16 * VTSTRIDE];
        #pragma unroll
        for (int r = 0; r < 4; ++r) {
            int row = 4 * g + r;
            pw[row * VTSTRIDE + r16]      = f2bf(p0[r]);
            pw[row * VTSTRIDE + 16 + r16] = f2bf(p1[r]);
        }
        bf16x8 pf = *(const bf16x8*)&pw[r16 * VTSTRIDE + 8 * g];

        #pragma unroll
        for (int dt = 0; dt < 8; ++dt) {
            #pragma unroll
            for (int r = 0; r < 4; ++r) o_acc[dt][r] *= alpha[r];
        }
        #pragma unroll
        for (int dt = 0; dt < 8; ++dt) {
            bf16x8 vf = *(const bf16x8*)&vt_lds[(16 * dt + r16) * VTSTRIDE + 8 * g];
            o_acc[dt] = __builtin_amdgcn_mfma_f32_16x16x32_bf16(pf, vf, o_acc[dt], 0, 0, 0);
        }
    }

    #pragma unroll
    for (int r = 0; r < 4; ++r) {
        float inv = 1.0f / l_run[r];
        int row = qb * 64 + wave * 16 + 4 * g + r;
        float* op = Oh + (size_t)row * DD + r16;
        #pragma unroll
        for (int dt = 0; dt < 8; ++dt)
            op[16 * dt] = o_acc[dt][r] * inv;
    }
}

extern "C" void kernel_launch(void* const* d_in, const int* in_sizes, int n_in,
                              void* d_out, int out_size, void* d_ws, size_t ws_size,
                              hipStream_t stream) {
    const float* q = (const float*)d_in[0];
    const float* k = (const float*)d_in[1];
    const float* v = (const float*)d_in[2];
    float* o = (float*)d_out;

    if (ws_size >= WS_NEED) {
        char* ws = (char*)d_ws;
        prep_k_kernel <<<dim3(NKV, NHEADS), 256, 0, stream>>>(k, ws);
        prep_vt_kernel<<<dim3(NKV, NHEADS), 256, 0, stream>>>(v, ws);
        attn_main_kernel<<<dim3(NQB * NHEADS), 256, 0, stream>>>(
            q, ws, ws + WS_K_BYTES, o);
    } else {
        attn_fwd_fallback<<<dim3(LQ_N / 64, NHEADS), 256, 0, stream>>>(q, k, v, o);
    }
}

// Round 4
// 104.140 us; speedup vs baseline: 6.4799x; 1.3194x over previous
//
#include <hip/hip_runtime.h>
#include <hip/hip_bf16.h>
#include <cstdint>

// Problem constants (B=2, H=16 -> 32 heads)
#define LQ_N   2048
#define LK_N   2048
#define DD     128
#define NHEADS 32
#define QBLK   128               // q rows per block (4 waves x 32 rows)
#define KVBLK  64
#define NKV    (LK_N / KVBLK)    // 32 kv tiles
#define NQB    (LQ_N / QBLK)     // 16 q blocks
#define SCALE  0.08838834764831845f            // 1/sqrt(128)
#define SCALE2 0.1275525003267101f             // SCALE * log2(e)

// ws layout: [K bf16 swizzled tiles][V^T bf16 swizzled tiles]
#define KTILE_BYTES (KVBLK * DD * 2)                        // 16 KiB per tile
#define WS_K_BYTES  ((size_t)NHEADS * NKV * KTILE_BYTES)    // 16 MiB
#define WS_NEED     (2 * WS_K_BYTES)                        // 32 MiB

#define PSTR 72   // prep_vt LDS row stride

typedef __attribute__((ext_vector_type(8)))  short bf16x8;
typedef __attribute__((ext_vector_type(4)))  float f32x4;
typedef __attribute__((ext_vector_type(16))) float f32x16;

#if __has_builtin(__builtin_amdgcn_exp2f)
#define EXP2F __builtin_amdgcn_exp2f
#else
#define EXP2F exp2f
#endif

__device__ inline unsigned short f2bf(float f) {
    union { float f; unsigned u; } x; x.f = f;
    unsigned r = (x.u + 0x7fffu + ((x.u >> 16) & 1u)) >> 16;  // RNE
    return (unsigned short)r;
}

__device__ inline unsigned cvt_pk_bf16(float lo, float hi) {
    unsigned r;
    asm("v_cvt_pk_bf16_f32 %0, %1, %2" : "=v"(r) : "v"(lo), "v"(hi));
    return r;
}

// Build P^T B-fragment (K=16 slice) from 8 softmax'd f32 regs.
// Source regs v0..v7 = C-layout rows {0,1,2,3, 8,9,10,11}+4h of a 32-row
// block; after the two permlane32_swap's each lane holds B[k=8h+j][q].
__device__ inline bf16x8 make_pfrag(float v0, float v1, float v2, float v3,
                                    float v4, float v5, float v6, float v7) {
    unsigned a0 = cvt_pk_bf16(v0, v1);
    unsigned a1 = cvt_pk_bf16(v2, v3);
    unsigned b0 = cvt_pk_bf16(v4, v5);
    unsigned b1 = cvt_pk_bf16(v6, v7);
    asm volatile("v_permlane32_swap_b32 %0, %1" : "+v"(a0), "+v"(b0));
    asm volatile("v_permlane32_swap_b32 %0, %1" : "+v"(a1), "+v"(b1));
    union { unsigned u[4]; bf16x8 v8; } u;
    u.u[0] = a0; u.u[1] = a1; u.u[2] = b0; u.u[3] = b1;
    return u.v8;
}

// ---------------- pre-pass A: K fp32 -> bf16*SCALE2, tile-major, XOR-swizzled
__global__ __launch_bounds__(256, 2)
void prep_k_kernel(const float* __restrict__ K, char* __restrict__ ws)
{
    const int tid  = threadIdx.x;
    const int kvt  = blockIdx.x;
    const int head = blockIdx.y;
    const float* Kh = K + ((size_t)head * LK_N + (size_t)kvt * KVBLK) * DD;
    char* dst = ws + ((size_t)head * NKV + kvt) * KTILE_BYTES;
    #pragma unroll
    for (int i = 0; i < 4; ++i) {
        int c = tid + 256 * i;          // 16B chunk id, 1024 per tile
        int row  = c >> 4;              // 0..63 (kv row)
        int col8 = c & 15;              // 8-elem group along D
        const float* src = Kh + (size_t)row * DD + col8 * 8;
        float4 a = *(const float4*)src;
        float4 b = *(const float4*)(src + 4);
        bf16x8 t;
        t[0] = (short)f2bf(a.x * SCALE2); t[1] = (short)f2bf(a.y * SCALE2);
        t[2] = (short)f2bf(a.z * SCALE2); t[3] = (short)f2bf(a.w * SCALE2);
        t[4] = (short)f2bf(b.x * SCALE2); t[5] = (short)f2bf(b.y * SCALE2);
        t[6] = (short)f2bf(b.z * SCALE2); t[7] = (short)f2bf(b.w * SCALE2);
        *(bf16x8*)(dst + row * 256 + ((col8 * 16) ^ ((row & 7) << 4))) = t;
    }
}

// ---------------- pre-pass B: V fp32 -> V^T bf16, tile-major, XOR-swizzled
__global__ __launch_bounds__(256, 2)
void prep_vt_kernel(const float* __restrict__ V, char* __restrict__ ws)
{
    __shared__ unsigned short vt[DD * PSTR];
    const int tid  = threadIdx.x;
    const int kvt  = blockIdx.x;
    const int head = blockIdx.y;
    const float* Vh = V + ((size_t)head * LK_N + (size_t)kvt * KVBLK) * DD;
    #pragma unroll
    for (int i = 0; i < 8; ++i) {
        int f = tid + 256 * i;          // float4 id, 2048 per tile
        int r  = f >> 5;                // kv row 0..63
        int c4 = f & 31;                // float4 along D
        float4 x = *(const float4*)(Vh + (size_t)r * DD + c4 * 4);
        vt[(c4 * 4 + 0) * PSTR + r] = f2bf(x.x);
        vt[(c4 * 4 + 1) * PSTR + r] = f2bf(x.y);
        vt[(c4 * 4 + 2) * PSTR + r] = f2bf(x.z);
        vt[(c4 * 4 + 3) * PSTR + r] = f2bf(x.w);
    }
    __syncthreads();
    char* dst = ws + WS_K_BYTES + ((size_t)head * NKV + kvt) * KTILE_BYTES;
    #pragma unroll
    for (int i = 0; i < 4; ++i) {
        int c = tid + 256 * i;          // 16B chunk id
        int d   = c >> 3;               // 0..127
        int kv8 = c & 7;                // 8-elem group along kv
        bf16x8 t = *(const bf16x8*)&vt[d * PSTR + kv8 * 8];
        *(bf16x8*)(dst + d * 128 + ((kv8 * 16) ^ ((d & 7) << 4))) = t;
    }
}

// ---------------- main attention kernel: 32x32 MFMA, fully transposed
__global__ __launch_bounds__(256, 2)
void attn_main_kernel(const float* __restrict__ Q, const char* __restrict__ kws,
                      const char* __restrict__ vws, float* __restrict__ O)
{
    __shared__ unsigned short kt_lds[KVBLK * DD];      // 16 KiB, swizzled image
    __shared__ unsigned short vt_lds[DD * KVBLK];      // 16 KiB, swizzled image

    const int tid  = threadIdx.x;
    const int lane = tid & 63;
    const int wave = tid >> 6;
    const int l31  = lane & 31;
    const int h    = lane >> 5;     // half: 0/1

    // XCD-aware bijective swizzle: 512 blocks, 8 XCDs, 64-block chunks
    const int bid  = blockIdx.x;
    const int sid  = (bid & 7) * (NQB * NHEADS / 8) + (bid >> 3);
    const int head = sid >> 4;       // /NQB
    const int qb   = sid & 15;       // %NQB

    const float* Qh = Q + (size_t)head * LQ_N * DD;
    float*       Oh = O + (size_t)head * LQ_N * DD;
    const char*  kt_g = kws + (size_t)head * NKV * KTILE_BYTES;
    const char*  vt_g = vws + (size_t)head * NKV * KTILE_BYTES;

    // ---- Q^T B-fragments: lane holds Q[q = qrow][d = 16*kd + 8*h + j]
    const int qrow = qb * QBLK + wave * 32 + l31;
    bf16x8 qf[8];
    {
        const float* qp = Qh + (size_t)qrow * DD + 8 * h;
        #pragma unroll
        for (int kd = 0; kd < 8; ++kd) {
            float4 a = *(const float4*)(qp + 16 * kd);
            float4 b = *(const float4*)(qp + 16 * kd + 4);
            bf16x8 t;
            t[0] = (short)f2bf(a.x); t[1] = (short)f2bf(a.y);
            t[2] = (short)f2bf(a.z); t[3] = (short)f2bf(a.w);
            t[4] = (short)f2bf(b.x); t[5] = (short)f2bf(b.y);
            t[6] = (short)f2bf(b.z); t[7] = (short)f2bf(b.w);
            qf[kd] = t;
        }
    }

    f32x16 o_acc[4];
    #pragma unroll
    for (int nt = 0; nt < 4; ++nt)
        #pragma unroll
        for (int i = 0; i < 16; ++i) o_acc[nt][i] = 0.f;
    float m_run = -1e30f, l_run = 0.f;

    // prologue: prefetch tile 0 into regs (16B chunks)
    const bf16x8* kg = (const bf16x8*)kt_g;
    const bf16x8* vg = (const bf16x8*)vt_g;
    bf16x8 skreg[4], svreg[4];
    #pragma unroll
    for (int i = 0; i < 4; ++i) { skreg[i] = kg[tid + 256 * i]; svreg[i] = vg[tid + 256 * i]; }

    const char* kb = (const char*)kt_lds;
    const char* vb = (const char*)vt_lds;
    const int swz = (l31 & 7) << 4;   // row&7 is same for row0/row1/d reads

    for (int t = 0; t < NKV; ++t) {
        __syncthreads();
        #pragma unroll
        for (int i = 0; i < 4; ++i) {
            *(bf16x8*)&kt_lds[(tid + 256 * i) * 8] = skreg[i];
            *(bf16x8*)&vt_lds[(tid + 256 * i) * 8] = svreg[i];
        }
        __syncthreads();

        if (t + 1 < NKV) {
            int base = (t + 1) * (KTILE_BYTES / 16);
            #pragma unroll
            for (int i = 0; i < 4; ++i) {
                skreg[i] = kg[base + tid + 256 * i];
                svreg[i] = vg[base + tid + 256 * i];
            }
        }

        // ---- S^T = K Q^T : lane holds S[kv][q=l31]; s0: kv block 0..31, s1: 32..63
        f32x16 s0, s1;
        #pragma unroll
        for (int i = 0; i < 16; ++i) { s0[i] = 0.f; s1[i] = 0.f; }
        __builtin_amdgcn_s_setprio(1);
        #pragma unroll
        for (int kd = 0; kd < 8; ++kd) {
            bf16x8 kf0 = *(const bf16x8*)(kb + l31 * 256        + ((32 * kd + 16 * h) ^ swz));
            bf16x8 kf1 = *(const bf16x8*)(kb + (32 + l31) * 256 + ((32 * kd + 16 * h) ^ swz));
            s0 = __builtin_amdgcn_mfma_f32_32x32x16_bf16(kf0, qf[kd], s0, 0, 0, 0);
            s1 = __builtin_amdgcn_mfma_f32_32x32x16_bf16(kf1, qf[kd], s1, 0, 0, 0);
        }
        __builtin_amdgcn_s_setprio(0);

        // ---- online softmax (log2 domain), q = l31 lane-local
        float pmax = s0[0];
        #pragma unroll
        for (int i = 1; i < 16; ++i) pmax = fmaxf(pmax, s0[i]);
        #pragma unroll
        for (int i = 0; i < 16; ++i) pmax = fmaxf(pmax, s1[i]);
        pmax = fmaxf(pmax, __shfl_xor(pmax, 32));

        if (!__all(pmax <= m_run + 8.0f)) {     // defer-max (T13)
            float mn = fmaxf(m_run, pmax);
            float al = EXP2F(m_run - mn);
            m_run = mn;
            l_run *= al;
            #pragma unroll
            for (int nt = 0; nt < 4; ++nt)
                #pragma unroll
                for (int i = 0; i < 16; ++i) o_acc[nt][i] *= al;
        }
        float sum = 0.f;
        #pragma unroll
        for (int i = 0; i < 16; ++i) { s0[i] = EXP2F(s0[i] - m_run); sum += s0[i]; }
        #pragma unroll
        for (int i = 0; i < 16; ++i) { s1[i] = EXP2F(s1[i] - m_run); sum += s1[i]; }
        sum += __shfl_xor(sum, 32);
        l_run += sum;

        // ---- P^T B-fragments, all in-register (cvt_pk + permlane32_swap)
        bf16x8 pf0 = make_pfrag(s0[0], s0[1], s0[2],  s0[3],  s0[4],  s0[5],  s0[6],  s0[7]);
        bf16x8 pf1 = make_pfrag(s0[8], s0[9], s0[10], s0[11], s0[12], s0[13], s0[14], s0[15]);
        bf16x8 pf2 = make_pfrag(s1[0], s1[1], s1[2],  s1[3],  s1[4],  s1[5],  s1[6],  s1[7]);
        bf16x8 pf3 = make_pfrag(s1[8], s1[9], s1[10], s1[11], s1[12], s1[13], s1[14], s1[15]);

        // ---- O^T += V^T P^T  (A = V^T rows d, B = P^T)
        __builtin_amdgcn_s_setprio(1);
        #pragma unroll
        for (int nt = 0; nt < 4; ++nt) {
            int d = 32 * nt + l31;
            const char* vrow = vb + d * 128;
            bf16x8 vf0 = *(const bf16x8*)(vrow + ((16 * h      ) ^ swz));
            bf16x8 vf1 = *(const bf16x8*)(vrow + ((32 + 16 * h ) ^ swz));
            bf16x8 vf2 = *(const bf16x8*)(vrow + ((64 + 16 * h ) ^ swz));
            bf16x8 vf3 = *(const bf16x8*)(vrow + ((96 + 16 * h ) ^ swz));
            o_acc[nt] = __builtin_amdgcn_mfma_f32_32x32x16_bf16(vf0, pf0, o_acc[nt], 0, 0, 0);
            o_acc[nt] = __builtin_amdgcn_mfma_f32_32x32x16_bf16(vf1, pf1, o_acc[nt], 0, 0, 0);
            o_acc[nt] = __builtin_amdgcn_mfma_f32_32x32x16_bf16(vf2, pf2, o_acc[nt], 0, 0, 0);
            o_acc[nt] = __builtin_amdgcn_mfma_f32_32x32x16_bf16(vf3, pf3, o_acc[nt], 0, 0, 0);
        }
        __builtin_amdgcn_s_setprio(0);
    }

    // ---- epilogue: O[q][d] = O^T / l ; lane owns col q = qrow, rows d
    float inv = 1.0f / l_run;
    float* op = Oh + (size_t)qrow * DD;
    #pragma unroll
    for (int nt = 0; nt < 4; ++nt)
        #pragma unroll
        for (int p = 0; p < 4; ++p) {
            int dbase = 32 * nt + 8 * p + 4 * h;
            float4 w;
            w.x = o_acc[nt][4 * p + 0] * inv;
            w.y = o_acc[nt][4 * p + 1] * inv;
            w.z = o_acc[nt][4 * p + 2] * inv;
            w.w = o_acc[nt][4 * p + 3] * inv;
            *(float4*)(op + dbase) = w;
        }
}

// ================= fallback (round-1 kernel, used if ws too small) ==========
#define KSTRIDE  136
#define VTSTRIDE 40
#define FKV 32

__global__ __launch_bounds__(256, 2)
void attn_fwd_fallback(const float* __restrict__ Q, const float* __restrict__ K,
                       const float* __restrict__ V, float* __restrict__ O)
{
    __shared__ unsigned short k_lds[FKV * KSTRIDE];
    __shared__ unsigned short vt_lds[DD * VTSTRIDE];
    __shared__ unsigned short p_lds2[4 * 16 * VTSTRIDE];

    const int tid  = threadIdx.x;
    const int lane = tid & 63;
    const int wave = tid >> 6;
    const int head = blockIdx.y;
    const int qb   = blockIdx.x;

    const float* Qh = Q + (size_t)head * LQ_N * DD;
    const float* Kh = K + (size_t)head * LK_N * DD;
    const float* Vh = V + (size_t)head * LK_N * DD;
    float*       Oh = O + (size_t)head * LQ_N * DD;

    const int r16 = lane & 15;
    const int g   = lane >> 4;

    const int qrow = qb * 64 + wave * 16 + r16;
    bf16x8 qf[4];
    {
        const float* qp = Qh + (size_t)qrow * DD + 8 * g;
        #pragma unroll
        for (int kt = 0; kt < 4; ++kt) {
            float4 a = *(const float4*)(qp + 32 * kt);
            float4 b = *(const float4*)(qp + 32 * kt + 4);
            bf16x8 t;
            t[0] = (short)f2bf(a.x * SCALE); t[1] = (short)f2bf(a.y * SCALE);
            t[2] = (short)f2bf(a.z * SCALE); t[3] = (short)f2bf(a.w * SCALE);
            t[4] = (short)f2bf(b.x * SCALE); t[5] = (short)f2bf(b.y * SCALE);
            t[6] = (short)f2bf(b.z * SCALE); t[7] = (short)f2bf(b.w * SCALE);
            qf[kt] = t;
        }
    }

    f32x4 o_acc[8];
    #pragma unroll
    for (int dt = 0; dt < 8; ++dt) o_acc[dt] = (f32x4){0.f, 0.f, 0.f, 0.f};
    float m_run[4], l_run[4];
    #pragma unroll
    for (int r = 0; r < 4; ++r) { m_run[r] = -1e30f; l_run[r] = 0.f; }

    for (int kv = 0; kv < LK_N / FKV; ++kv) {
        const float* Kt = Kh + (size_t)kv * FKV * DD;
        const float* Vt = Vh + (size_t)kv * FKV * DD;
        __syncthreads();
        #pragma unroll
        for (int i = 0; i < 4; ++i) {
            int f = tid + 256 * i;
            int row = f >> 5, colf = f & 31;
            float4 x = *(const float4*)(Kt + (size_t)row * DD + colf * 4);
            ushort4 pk;
            pk.x = f2bf(x.x); pk.y = f2bf(x.y); pk.z = f2bf(x.z); pk.w = f2bf(x.w);
            *(ushort4*)(&k_lds[row * KSTRIDE + colf * 4]) = pk;
        }
        #pragma unroll
        for (int i = 0; i < 4; ++i) {
            int f = tid + 256 * i;
            int row = f >> 5, colf = f & 31;
            float4 x = *(const float4*)(Vt + (size_t)row * DD + colf * 4);
            vt_lds[(colf * 4 + 0) * VTSTRIDE + row] = f2bf(x.x);
            vt_lds[(colf * 4 + 1) * VTSTRIDE + row] = f2bf(x.y);
            vt_lds[(colf * 4 + 2) * VTSTRIDE + row] = f2bf(x.z);
            vt_lds[(colf * 4 + 3) * VTSTRIDE + row] = f2bf(x.w);
        }
        __syncthreads();

        f32x4 s0 = (f32x4){0.f,0.f,0.f,0.f};
        f32x4 s1 = (f32x4){0.f,0.f,0.f,0.f};
        #pragma unroll
        for (int kt = 0; kt < 4; ++kt) {
            bf16x8 kf0 = *(const bf16x8*)&k_lds[(r16)      * KSTRIDE + 32 * kt + 8 * g];
            bf16x8 kf1 = *(const bf16x8*)&k_lds[(16 + r16) * KSTRIDE + 32 * kt + 8 * g];
            s0 = __builtin_amdgcn_mfma_f32_16x16x32_bf16(qf[kt], kf0, s0, 0, 0, 0);
            s1 = __builtin_amdgcn_mfma_f32_16x16x32_bf16(qf[kt], kf1, s1, 0, 0, 0);
        }

        float alpha[4];
        f32x4 p0, p1;
        #pragma unroll
        for (int r = 0; r < 4; ++r) {
            float t = fmaxf(s0[r], s1[r]);
            t = fmaxf(t, __shfl_xor(t, 1));
            t = fmaxf(t, __shfl_xor(t, 2));
            t = fmaxf(t, __shfl_xor(t, 4));
            t = fmaxf(t, __shfl_xor(t, 8));
            float mn = fmaxf(m_run[r], t);
            alpha[r] = __expf(m_run[r] - mn);
            m_run[r] = mn;
            p0[r] = __expf(s0[r] - mn);
            p1[r] = __expf(s1[r] - mn);
            float su = p0[r] + p1[r];
            su += __shfl_xor(su, 1);
            su += __shfl_xor(su, 2);
            su += __shfl_xor(su, 4);
            su += __shfl_xor(su, 8);
            l_run[r] = l_run[r] * alpha[r] + su;
        }

        unsigned short* pw = &p_lds2[wave * 16 * VTSTRIDE];
        #pragma unroll
        for (int r = 0; r < 4; ++r) {
            int row = 4 * g + r;
            pw[row * VTSTRIDE + r16]      = f2bf(p0[r]);
            pw[row * VTSTRIDE + 16 + r16] = f2bf(p1[r]);
        }
        bf16x8 pf = *(const bf16x8*)&pw[r16 * VTSTRIDE + 8 * g];

        #pragma unroll
        for (int dt = 0; dt < 8; ++dt) {
            #pragma unroll
            for (int r = 0; r < 4; ++r) o_acc[dt][r] *= alpha[r];
        }
        #pragma unroll
        for (int dt = 0; dt < 8; ++dt) {
            bf16x8 vf = *(const bf16x8*)&vt_lds[(16 * dt + r16) * VTSTRIDE + 8 * g];
            o_acc[dt] = __builtin_amdgcn_mfma_f32_16x16x32_bf16(pf, vf, o_acc[dt], 0, 0, 0);
        }
    }

    #pragma unroll
    for (int r = 0; r < 4; ++r) {
        float inv = 1.0f / l_run[r];
        int row = qb * 64 + wave * 16 + 4 * g + r;
        float* op = Oh + (size_t)row * DD + r16;
        #pragma unroll
        for (int dt = 0; dt < 8; ++dt)
            op[16 * dt] = o_acc[dt][r] * inv;
    }
}

extern "C" void kernel_launch(void* const* d_in, const int* in_sizes, int n_in,
                              void* d_out, int out_size, void* d_ws, size_t ws_size,
                              hipStream_t stream) {
    const float* q = (const float*)d_in[0];
    const float* k = (const float*)d_in[1];
    const float* v = (const float*)d_in[2];
    float* o = (float*)d_out;

    if (ws_size >= WS_NEED) {
        char* ws = (char*)d_ws;
        prep_k_kernel <<<dim3(NKV, NHEADS), 256, 0, stream>>>(k, ws);
        prep_vt_kernel<<<dim3(NKV, NHEADS), 256, 0, stream>>>(v, ws);
        attn_main_kernel<<<dim3(NQB * NHEADS), 256, 0, stream>>>(
            q, ws, ws + WS_K_BYTES, o);
    } else {
        attn_fwd_fallback<<<dim3(LQ_N / 64, NHEADS), 256, 0, stream>>>(q, k, v, o);
    }
}

// Round 5
// 101.141 us; speedup vs baseline: 6.6721x; 1.0297x over previous
//
#include <hip/hip_runtime.h>
#include <hip/hip_bf16.h>
#include <cstdint>

// Problem constants (B=2, H=16 -> 32 heads)
#define LQ_N   2048
#define LK_N   2048
#define DD     128
#define NHEADS 32
#define QBLK   128               // q rows per block (4 waves x 32 rows)
#define KVBLK  64
#define NKV    (LK_N / KVBLK)    // 32 kv tiles
#define NQB    (LQ_N / QBLK)     // 16 q blocks
#define SCALE  0.08838834764831845f            // 1/sqrt(128)
#define SCALE2 0.1275525003267101f             // SCALE * log2(e)

// ws layout: [K tiles][V^T tiles], each tile 16 KiB in granule-transposed
// order:  K  tile: byte (g*64 + r)*16,  g=0..15 (8 d-elems), r=0..63 (kv)
//         V^T tile: byte (g*128 + d)*16, g=0..7 (8 kv-elems), d=0..127
#define KTILE_BYTES (KVBLK * DD * 2)                        // 16 KiB per tile
#define WS_K_BYTES  ((size_t)NHEADS * NKV * KTILE_BYTES)    // 16 MiB
#define WS_NEED     (2 * WS_K_BYTES)                        // 32 MiB

#define PSTR 72   // prep_vt LDS row stride

typedef __attribute__((ext_vector_type(8)))  short bf16x8;
typedef __attribute__((ext_vector_type(4)))  float f32x4;
typedef __attribute__((ext_vector_type(16))) float f32x16;

#if __has_builtin(__builtin_amdgcn_exp2f)
#define EXP2F __builtin_amdgcn_exp2f
#else
#define EXP2F exp2f
#endif

__device__ inline unsigned short f2bf(float f) {
    union { float f; unsigned u; } x; x.f = f;
    unsigned r = (x.u + 0x7fffu + ((x.u >> 16) & 1u)) >> 16;  // RNE
    return (unsigned short)r;
}

__device__ inline unsigned cvt_pk_bf16(float lo, float hi) {
    unsigned r;
    asm("v_cvt_pk_bf16_f32 %0, %1, %2" : "=v"(r) : "v"(lo), "v"(hi));
    return r;
}

// Build P^T B-fragment (K=16 slice) from 8 softmax'd f32 regs (as R4, verified).
__device__ inline bf16x8 make_pfrag(float v0, float v1, float v2, float v3,
                                    float v4, float v5, float v6, float v7) {
    unsigned a0 = cvt_pk_bf16(v0, v1);
    unsigned a1 = cvt_pk_bf16(v2, v3);
    unsigned b0 = cvt_pk_bf16(v4, v5);
    unsigned b1 = cvt_pk_bf16(v6, v7);
    asm volatile("v_permlane32_swap_b32 %0, %1" : "+v"(a0), "+v"(b0));
    asm volatile("v_permlane32_swap_b32 %0, %1" : "+v"(a1), "+v"(b1));
    union { unsigned u[4]; bf16x8 v8; } u;
    u.u[0] = a0; u.u[1] = a1; u.u[2] = b0; u.u[3] = b1;
    return u.v8;
}

__device__ inline void gld16(const char* g, const char* l) {
    __builtin_amdgcn_global_load_lds(
        (const __attribute__((address_space(1))) unsigned int*)g,
        (__attribute__((address_space(3))) unsigned int*)l,
        16, 0, 0);
}

// ---------------- pre-pass A: K fp32 -> bf16*SCALE2, granule-transposed tiles
__global__ __launch_bounds__(256, 2)
void prep_k_kernel(const float* __restrict__ K, char* __restrict__ ws)
{
    __shared__ unsigned short kt[KVBLK * 136];   // [64][128] pad->136
    const int tid  = threadIdx.x;
    const int kvt  = blockIdx.x;
    const int head = blockIdx.y;
    const float* Kh = K + ((size_t)head * LK_N + (size_t)kvt * KVBLK) * DD;
    #pragma unroll
    for (int i = 0; i < 4; ++i) {
        int c = tid + 256 * i;          // 16B chunk id, 1024 per tile
        int r  = c >> 4;                // kv row 0..63
        int c8 = c & 15;                // 8-elem group along D
        const float* src = Kh + (size_t)r * DD + c8 * 8;
        float4 a = *(const float4*)src;
        float4 b = *(const float4*)(src + 4);
        bf16x8 t;
        t[0] = (short)f2bf(a.x * SCALE2); t[1] = (short)f2bf(a.y * SCALE2);
        t[2] = (short)f2bf(a.z * SCALE2); t[3] = (short)f2bf(a.w * SCALE2);
        t[4] = (short)f2bf(b.x * SCALE2); t[5] = (short)f2bf(b.y * SCALE2);
        t[6] = (short)f2bf(b.z * SCALE2); t[7] = (short)f2bf(b.w * SCALE2);
        *(bf16x8*)&kt[r * 136 + c8 * 8] = t;     // 272B rows: 16B-aligned
    }
    __syncthreads();
    char* dst = ws + ((size_t)head * NKV + kvt) * KTILE_BYTES;
    #pragma unroll
    for (int i = 0; i < 4; ++i) {
        int c = tid + 256 * i;
        int g = c >> 6;                 // granule col 0..15
        int r = c & 63;                 // row
        bf16x8 t = *(const bf16x8*)&kt[r * 136 + g * 8];
        *(bf16x8*)(dst + c * 16) = t;   // linear coalesced write
    }
}

// ---------------- pre-pass B: V fp32 -> V^T bf16, granule-transposed tiles
__global__ __launch_bounds__(256, 2)
void prep_vt_kernel(const float* __restrict__ V, char* __restrict__ ws)
{
    __shared__ unsigned short vt[DD * PSTR];     // [128][64] pad->72
    const int tid  = threadIdx.x;
    const int kvt  = blockIdx.x;
    const int head = blockIdx.y;
    const float* Vh = V + ((size_t)head * LK_N + (size_t)kvt * KVBLK) * DD;
    #pragma unroll
    for (int i = 0; i < 8; ++i) {
        int f = tid + 256 * i;          // float4 id, 2048 per tile
        int r  = f >> 5;                // kv row 0..63
        int c4 = f & 31;                // float4 along D
        float4 x = *(const float4*)(Vh + (size_t)r * DD + c4 * 4);
        vt[(c4 * 4 + 0) * PSTR + r] = f2bf(x.x);
        vt[(c4 * 4 + 1) * PSTR + r] = f2bf(x.y);
        vt[(c4 * 4 + 2) * PSTR + r] = f2bf(x.z);
        vt[(c4 * 4 + 3) * PSTR + r] = f2bf(x.w);
    }
    __syncthreads();
    char* dst = ws + WS_K_BYTES + ((size_t)head * NKV + kvt) * KTILE_BYTES;
    #pragma unroll
    for (int i = 0; i < 4; ++i) {
        int c = tid + 256 * i;
        int g = c >> 7;                 // granule col 0..7 (kv)
        int d = c & 127;                // row (d)
        bf16x8 t = *(const bf16x8*)&vt[d * PSTR + g * 8];  // 144B rows: aligned
        *(bf16x8*)(dst + c * 16) = t;
    }
}

// ---------------- main attention kernel: 32x32 MFMA, gload_lds double-buffer
__global__ __launch_bounds__(256, 2)
void attn_main_kernel(const float* __restrict__ Q, const char* __restrict__ kws,
                      const char* __restrict__ vws, float* __restrict__ O)
{
    __shared__ unsigned short kt_lds[2][KVBLK * DD];   // 2 x 16 KiB
    __shared__ unsigned short vt_lds[2][DD * KVBLK];   // 2 x 16 KiB

    const int tid  = threadIdx.x;
    const int lane = tid & 63;
    const int wave = tid >> 6;
    const int l31  = lane & 31;
    const int h    = lane >> 5;     // half: 0/1

    // XCD-aware bijective swizzle: 512 blocks, 8 XCDs, 64-block chunks
    const int bid  = blockIdx.x;
    const int sid  = (bid & 7) * (NQB * NHEADS / 8) + (bid >> 3);
    const int head = sid >> 4;       // /NQB
    const int qb   = sid & 15;       // %NQB

    const float* Qh = Q + (size_t)head * LQ_N * DD;
    float*       Oh = O + (size_t)head * LQ_N * DD;
    const char*  kt_g = kws + (size_t)head * NKV * KTILE_BYTES;
    const char*  vt_g = vws + (size_t)head * NKV * KTILE_BYTES;

    // ---- Q^T B-fragments: lane holds Q[q = qrow][d = 16*kd + 8*h + j]
    const int qrow = qb * QBLK + wave * 32 + l31;
    bf16x8 qf[8];
    {
        const float* qp = Qh + (size_t)qrow * DD + 8 * h;
        #pragma unroll
        for (int kd = 0; kd < 8; ++kd) {
            float4 a = *(const float4*)(qp + 16 * kd);
            float4 b = *(const float4*)(qp + 16 * kd + 4);
            bf16x8 t;
            t[0] = (short)f2bf(a.x); t[1] = (short)f2bf(a.y);
            t[2] = (short)f2bf(a.z); t[3] = (short)f2bf(a.w);
            t[4] = (short)f2bf(b.x); t[5] = (short)f2bf(b.y);
            t[6] = (short)f2bf(b.z); t[7] = (short)f2bf(b.w);
            qf[kd] = t;
        }
    }
    // Drain Q loads so our manual vmcnt bookkeeping below is exact.
    asm volatile("s_waitcnt vmcnt(0)" ::: "memory");

    f32x16 o_acc[4];
    #pragma unroll
    for (int nt = 0; nt < 4; ++nt)
        #pragma unroll
        for (int i = 0; i < 16; ++i) o_acc[nt][i] = 0.f;
    float m_run = -1e30f, l_run = 0.f;

    // stage tile t into buffer b: 8 x global_load_lds (4 K + 4 V), linear image
    auto issue = [&](int t, int b) {
        const char* ks = kt_g + (size_t)t * KTILE_BYTES;
        const char* vs = vt_g + (size_t)t * KTILE_BYTES;
        const char* kl = (const char*)&kt_lds[b][0];
        const char* vl = (const char*)&vt_lds[b][0];
        #pragma unroll
        for (int i = 0; i < 4; ++i) {
            int off = (tid + 256 * i) * 16;
            gld16(ks + off, kl + off);
            gld16(vs + off, vl + off);
        }
    };
    issue(0, 0);
    issue(1, 1);

    for (int t = 0; t < NKV; ++t) {
        // wait for tile t's 8 loads (tile t+1's 8 may stay in flight)
        if (t < NKV - 1) asm volatile("s_waitcnt vmcnt(8)" ::: "memory");
        else             asm volatile("s_waitcnt vmcnt(0)" ::: "memory");
        __builtin_amdgcn_s_barrier();

        const char* kb = (const char*)&kt_lds[t & 1][0];
        const char* vb = (const char*)&vt_lds[t & 1][0];

        // ---- S^T = K Q^T : lane holds S[kv][q=l31]
        f32x16 s0, s1;
        #pragma unroll
        for (int i = 0; i < 16; ++i) { s0[i] = 0.f; s1[i] = 0.f; }
        __builtin_amdgcn_s_setprio(1);
        #pragma unroll
        for (int kd = 0; kd < 8; ++kd) {
            int g = 2 * kd + h;
            bf16x8 kf0 = *(const bf16x8*)(kb + ((g * 64 + l31) << 4));
            bf16x8 kf1 = *(const bf16x8*)(kb + ((g * 64 + 32 + l31) << 4));
            s0 = __builtin_amdgcn_mfma_f32_32x32x16_bf16(kf0, qf[kd], s0, 0, 0, 0);
            s1 = __builtin_amdgcn_mfma_f32_32x32x16_bf16(kf1, qf[kd], s1, 0, 0, 0);
        }
        __builtin_amdgcn_s_setprio(0);

        // ---- online softmax (log2 domain), q = l31 lane-local
        float pmax = s0[0];
        #pragma unroll
        for (int i = 1; i < 16; ++i) pmax = fmaxf(pmax, s0[i]);
        #pragma unroll
        for (int i = 0; i < 16; ++i) pmax = fmaxf(pmax, s1[i]);
        pmax = fmaxf(pmax, __shfl_xor(pmax, 32));

        if (!__all(pmax <= m_run + 8.0f)) {     // defer-max (T13)
            float mn = fmaxf(m_run, pmax);
            float al = EXP2F(m_run - mn);
            m_run = mn;
            l_run *= al;
            #pragma unroll
            for (int nt = 0; nt < 4; ++nt)
                #pragma unroll
                for (int i = 0; i < 16; ++i) o_acc[nt][i] *= al;
        }
        float sum = 0.f;
        #pragma unroll
        for (int i = 0; i < 16; ++i) { s0[i] = EXP2F(s0[i] - m_run); sum += s0[i]; }
        #pragma unroll
        for (int i = 0; i < 16; ++i) { s1[i] = EXP2F(s1[i] - m_run); sum += s1[i]; }
        sum += __shfl_xor(sum, 32);
        l_run += sum;

        // ---- P^T B-fragments, in-register (cvt_pk + permlane32_swap)
        bf16x8 pf0 = make_pfrag(s0[0], s0[1], s0[2],  s0[3],  s0[4],  s0[5],  s0[6],  s0[7]);
        bf16x8 pf1 = make_pfrag(s0[8], s0[9], s0[10], s0[11], s0[12], s0[13], s0[14], s0[15]);
        bf16x8 pf2 = make_pfrag(s1[0], s1[1], s1[2],  s1[3],  s1[4],  s1[5],  s1[6],  s1[7]);
        bf16x8 pf3 = make_pfrag(s1[8], s1[9], s1[10], s1[11], s1[12], s1[13], s1[14], s1[15]);

        // ---- O^T += V^T P^T
        __builtin_amdgcn_s_setprio(1);
        #pragma unroll
        for (int nt = 0; nt < 4; ++nt) {
            int d = 32 * nt + l31;
            bf16x8 vf0 = *(const bf16x8*)(vb + (((0 + h) * 128 + d) << 4));
            bf16x8 vf1 = *(const bf16x8*)(vb + (((2 + h) * 128 + d) << 4));
            bf16x8 vf2 = *(const bf16x8*)(vb + (((4 + h) * 128 + d) << 4));
            bf16x8 vf3 = *(const bf16x8*)(vb + (((6 + h) * 128 + d) << 4));
            o_acc[nt] = __builtin_amdgcn_mfma_f32_32x32x16_bf16(vf0, pf0, o_acc[nt], 0, 0, 0);
            o_acc[nt] = __builtin_amdgcn_mfma_f32_32x32x16_bf16(vf1, pf1, o_acc[nt], 0, 0, 0);
            o_acc[nt] = __builtin_amdgcn_mfma_f32_32x32x16_bf16(vf2, pf2, o_acc[nt], 0, 0, 0);
            o_acc[nt] = __builtin_amdgcn_mfma_f32_32x32x16_bf16(vf3, pf3, o_acc[nt], 0, 0, 0);
        }
        __builtin_amdgcn_s_setprio(0);

        __builtin_amdgcn_s_barrier();          // all waves done reading buf[t&1]
        if (t + 2 < NKV) issue(t + 2, t & 1);  // overwrite it with tile t+2
    }

    // ---- epilogue: O[q][d] = O^T / l ; lane owns col q = qrow
    float inv = 1.0f / l_run;
    float* op = Oh + (size_t)qrow * DD;
    #pragma unroll
    for (int nt = 0; nt < 4; ++nt)
        #pragma unroll
        for (int p = 0; p < 4; ++p) {
            int dbase = 32 * nt + 8 * p + 4 * h;
            float4 w;
            w.x = o_acc[nt][4 * p + 0] * inv;
            w.y = o_acc[nt][4 * p + 1] * inv;
            w.z = o_acc[nt][4 * p + 2] * inv;
            w.w = o_acc[nt][4 * p + 3] * inv;
            *(float4*)(op + dbase) = w;
        }
}

// ================= fallback (round-1 kernel, used if ws too small) ==========
#define KSTRIDE  136
#define VTSTRIDE 40
#define FKV 32

__global__ __launch_bounds__(256, 2)
void attn_fwd_fallback(const float* __restrict__ Q, const float* __restrict__ K,
                       const float* __restrict__ V, float* __restrict__ O)
{
    __shared__ unsigned short k_lds[FKV * KSTRIDE];
    __shared__ unsigned short vt_lds[DD * VTSTRIDE];
    __shared__ unsigned short p_lds2[4 * 16 * VTSTRIDE];

    const int tid  = threadIdx.x;
    const int lane = tid & 63;
    const int wave = tid >> 6;
    const int head = blockIdx.y;
    const int qb   = blockIdx.x;

    const float* Qh = Q + (size_t)head * LQ_N * DD;
    const float* Kh = K + (size_t)head * LK_N * DD;
    const float* Vh = V + (size_t)head * LK_N * DD;
    float*       Oh = O + (size_t)head * LQ_N * DD;

    const int r16 = lane & 15;
    const int g   = lane >> 4;

    const int qrow = qb * 64 + wave * 16 + r16;
    bf16x8 qf[4];
    {
        const float* qp = Qh + (size_t)qrow * DD + 8 * g;
        #pragma unroll
        for (int kt = 0; kt < 4; ++kt) {
            float4 a = *(const float4*)(qp + 32 * kt);
            float4 b = *(const float4*)(qp + 32 * kt + 4);
            bf16x8 t;
            t[0] = (short)f2bf(a.x * SCALE); t[1] = (short)f2bf(a.y * SCALE);
            t[2] = (short)f2bf(a.z * SCALE); t[3] = (short)f2bf(a.w * SCALE);
            t[4] = (short)f2bf(b.x * SCALE); t[5] = (short)f2bf(b.y * SCALE);
            t[6] = (short)f2bf(b.z * SCALE); t[7] = (short)f2bf(b.w * SCALE);
            qf[kt] = t;
        }
    }

    f32x4 o_acc[8];
    #pragma unroll
    for (int dt = 0; dt < 8; ++dt) o_acc[dt] = (f32x4){0.f, 0.f, 0.f, 0.f};
    float m_run[4], l_run[4];
    #pragma unroll
    for (int r = 0; r < 4; ++r) { m_run[r] = -1e30f; l_run[r] = 0.f; }

    for (int kv = 0; kv < LK_N / FKV; ++kv) {
        const float* Kt = Kh + (size_t)kv * FKV * DD;
        const float* Vt = Vh + (size_t)kv * FKV * DD;
        __syncthreads();
        #pragma unroll
        for (int i = 0; i < 4; ++i) {
            int f = tid + 256 * i;
            int row = f >> 5, colf = f & 31;
            float4 x = *(const float4*)(Kt + (size_t)row * DD + colf * 4);
            ushort4 pk;
            pk.x = f2bf(x.x); pk.y = f2bf(x.y); pk.z = f2bf(x.z); pk.w = f2bf(x.w);
            *(ushort4*)(&k_lds[row * KSTRIDE + colf * 4]) = pk;
        }
        #pragma unroll
        for (int i = 0; i < 4; ++i) {
            int f = tid + 256 * i;
            int row = f >> 5, colf = f & 31;
            float4 x = *(const float4*)(Vt + (size_t)row * DD + colf * 4);
            vt_lds[(colf * 4 + 0) * VTSTRIDE + row] = f2bf(x.x);
            vt_lds[(colf * 4 + 1) * VTSTRIDE + row] = f2bf(x.y);
            vt_lds[(colf * 4 + 2) * VTSTRIDE + row] = f2bf(x.z);
            vt_lds[(colf * 4 + 3) * VTSTRIDE + row] = f2bf(x.w);
        }
        __syncthreads();

        f32x4 s0 = (f32x4){0.f,0.f,0.f,0.f};
        f32x4 s1 = (f32x4){0.f,0.f,0.f,0.f};
        #pragma unroll
        for (int kt = 0; kt < 4; ++kt) {
            bf16x8 kf0 = *(const bf16x8*)&k_lds[(r16)      * KSTRIDE + 32 * kt + 8 * g];
            bf16x8 kf1 = *(const bf16x8*)&k_lds[(16 + r16) * KSTRIDE + 32 * kt + 8 * g];
            s0 = __builtin_amdgcn_mfma_f32_16x16x32_bf16(qf[kt], kf0, s0, 0, 0, 0);
            s1 = __builtin_amdgcn_mfma_f32_16x16x32_bf16(qf[kt], kf1, s1, 0, 0, 0);
        }

        float alpha[4];
        f32x4 p0, p1;
        #pragma unroll
        for (int r = 0; r < 4; ++r) {
            float t = fmaxf(s0[r], s1[r]);
            t = fmaxf(t, __shfl_xor(t, 1));
            t = fmaxf(t, __shfl_xor(t, 2));
            t = fmaxf(t, __shfl_xor(t, 4));
            t = fmaxf(t, __shfl_xor(t, 8));
            float mn = fmaxf(m_run[r], t);
            alpha[r] = __expf(m_run[r] - mn);
            m_run[r] = mn;
            p0[r] = __expf(s0[r] - mn);
            p1[r] = __expf(s1[r] - mn);
            float su = p0[r] + p1[r];
            su += __shfl_xor(su, 1);
            su += __shfl_xor(su, 2);
            su += __shfl_xor(su, 4);
            su += __shfl_xor(su, 8);
            l_run[r] = l_run[r] * alpha[r] + su;
        }

        unsigned short* pw = &p_lds2[wave * 16 * VTSTRIDE];
        #pragma unroll
        for (int r = 0; r < 4; ++r) {
            int row = 4 * g + r;
            pw[row * VTSTRIDE + r16]      = f2bf(p0[r]);
            pw[row * VTSTRIDE + 16 + r16] = f2bf(p1[r]);
        }
        bf16x8 pf = *(const bf16x8*)&pw[r16 * VTSTRIDE + 8 * g];

        #pragma unroll
        for (int dt = 0; dt < 8; ++dt) {
            #pragma unroll
            for (int r = 0; r < 4; ++r) o_acc[dt][r] *= alpha[r];
        }
        #pragma unroll
        for (int dt = 0; dt < 8; ++dt) {
            bf16x8 vf = *(const bf16x8*)&vt_lds[(16 * dt + r16) * VTSTRIDE + 8 * g];
            o_acc[dt] = __builtin_amdgcn_mfma_f32_16x16x32_bf16(pf, vf, o_acc[dt], 0, 0, 0);
        }
    }

    #pragma unroll
    for (int r = 0; r < 4; ++r) {
        float inv = 1.0f / l_run[r];
        int row = qb * 64 + wave * 16 + 4 * g + r;
        float* op = Oh + (size_t)row * DD + r16;
        #pragma unroll
        for (int dt = 0; dt < 8; ++dt)
            op[16 * dt] = o_acc[dt][r] * inv;
    }
}

extern "C" void kernel_launch(void* const* d_in, const int* in_sizes, int n_in,
                              void* d_out, int out_size, void* d_ws, size_t ws_size,
                              hipStream_t stream) {
    const float* q = (const float*)d_in[0];
    const float* k = (const float*)d_in[1];
    const float* v = (const float*)d_in[2];
    float* o = (float*)d_out;

    if (ws_size >= WS_NEED) {
        char* ws = (char*)d_ws;
        prep_k_kernel <<<dim3(NKV, NHEADS), 256, 0, stream>>>(k, ws);
        prep_vt_kernel<<<dim3(NKV, NHEADS), 256, 0, stream>>>(v, ws);
        attn_main_kernel<<<dim3(NQB * NHEADS), 256, 0, stream>>>(
            q, ws, ws + WS_K_BYTES, o);
    } else {
        attn_fwd_fallback<<<dim3(LQ_N / 64, NHEADS), 256, 0, stream>>>(q, k, v, o);
    }
}

// Round 6
// 100.782 us; speedup vs baseline: 6.6959x; 1.0036x over previous
//
#include <hip/hip_runtime.h>
#include <hip/hip_bf16.h>
#include <cstdint>

// Problem constants (B=2, H=16 -> 32 heads)
#define LQ_N   2048
#define LK_N   2048
#define DD     128
#define NHEADS 32
#define QBLK   128               // q rows per block (4 waves x 32 rows)
#define KVBLK  64
#define NKV    (LK_N / KVBLK)    // 32 kv tiles
#define NQB    (LQ_N / QBLK)     // 16 q blocks
#define SCALE  0.08838834764831845f            // 1/sqrt(128)
#define SCALE2 0.1275525003267101f             // SCALE * log2(e)

// ws layout: [K tiles][V^T tiles], each tile 16 KiB in granule-transposed
// order:  K  tile: byte (g*64 + r)*16,  g=0..15 (8 d-elems), r=0..63 (kv)
//         V^T tile: byte (g*128 + d)*16, g=0..7 (8 kv-elems), d=0..127
#define KTILE_BYTES (KVBLK * DD * 2)                        // 16 KiB per tile
#define WS_K_BYTES  ((size_t)NHEADS * NKV * KTILE_BYTES)    // 16 MiB
#define WS_NEED     (2 * WS_K_BYTES)                        // 32 MiB

// main-kernel dynamic LDS: K double-buffer + V triple-buffer
#define KB_OFF(b)   ((b) * KTILE_BYTES)
#define VB_OFF(s)   (2 * KTILE_BYTES + (s) * KTILE_BYTES)
#define SMEM_MAIN   (5 * KTILE_BYTES)                       // 80 KiB

#define PSTR 72   // prep_vt LDS row stride

typedef __attribute__((ext_vector_type(8)))  short bf16x8;
typedef __attribute__((ext_vector_type(4)))  float f32x4;
typedef __attribute__((ext_vector_type(16))) float f32x16;

#if __has_builtin(__builtin_amdgcn_exp2f)
#define EXP2F __builtin_amdgcn_exp2f
#else
#define EXP2F exp2f
#endif

__device__ inline unsigned short f2bf(float f) {
    union { float f; unsigned u; } x; x.f = f;
    unsigned r = (x.u + 0x7fffu + ((x.u >> 16) & 1u)) >> 16;  // RNE
    return (unsigned short)r;
}

__device__ inline unsigned cvt_pk_bf16(float lo, float hi) {
    unsigned r;
    asm("v_cvt_pk_bf16_f32 %0, %1, %2" : "=v"(r) : "v"(lo), "v"(hi));
    return r;
}

// Build P^T B-fragment (K=16 slice) from 8 softmax'd f32 regs (verified R4).
__device__ inline bf16x8 make_pfrag(float v0, float v1, float v2, float v3,
                                    float v4, float v5, float v6, float v7) {
    unsigned a0 = cvt_pk_bf16(v0, v1);
    unsigned a1 = cvt_pk_bf16(v2, v3);
    unsigned b0 = cvt_pk_bf16(v4, v5);
    unsigned b1 = cvt_pk_bf16(v6, v7);
    asm volatile("v_permlane32_swap_b32 %0, %1" : "+v"(a0), "+v"(b0));
    asm volatile("v_permlane32_swap_b32 %0, %1" : "+v"(a1), "+v"(b1));
    union { unsigned u[4]; bf16x8 v8; } u;
    u.u[0] = a0; u.u[1] = a1; u.u[2] = b0; u.u[3] = b1;
    return u.v8;
}

__device__ inline void gld16(const char* g, const char* l) {
    __builtin_amdgcn_global_load_lds(
        (const __attribute__((address_space(1))) unsigned int*)g,
        (__attribute__((address_space(3))) unsigned int*)l,
        16, 0, 0);
}

// ---------------- pre-pass A: K fp32 -> bf16*SCALE2, granule-transposed tiles
__global__ __launch_bounds__(256, 2)
void prep_k_kernel(const float* __restrict__ K, char* __restrict__ ws)
{
    __shared__ unsigned short kt[KVBLK * 136];   // [64][128] pad->136
    const int tid  = threadIdx.x;
    const int kvt  = blockIdx.x;
    const int head = blockIdx.y;
    const float* Kh = K + ((size_t)head * LK_N + (size_t)kvt * KVBLK) * DD;
    #pragma unroll
    for (int i = 0; i < 4; ++i) {
        int c = tid + 256 * i;          // 16B chunk id, 1024 per tile
        int r  = c >> 4;                // kv row 0..63
        int c8 = c & 15;                // 8-elem group along D
        const float* src = Kh + (size_t)r * DD + c8 * 8;
        float4 a = *(const float4*)src;
        float4 b = *(const float4*)(src + 4);
        bf16x8 t;
        t[0] = (short)f2bf(a.x * SCALE2); t[1] = (short)f2bf(a.y * SCALE2);
        t[2] = (short)f2bf(a.z * SCALE2); t[3] = (short)f2bf(a.w * SCALE2);
        t[4] = (short)f2bf(b.x * SCALE2); t[5] = (short)f2bf(b.y * SCALE2);
        t[6] = (short)f2bf(b.z * SCALE2); t[7] = (short)f2bf(b.w * SCALE2);
        *(bf16x8*)&kt[r * 136 + c8 * 8] = t;
    }
    __syncthreads();
    char* dst = ws + ((size_t)head * NKV + kvt) * KTILE_BYTES;
    #pragma unroll
    for (int i = 0; i < 4; ++i) {
        int c = tid + 256 * i;
        int g = c >> 6;                 // granule col 0..15
        int r = c & 63;                 // row
        bf16x8 t = *(const bf16x8*)&kt[r * 136 + g * 8];
        *(bf16x8*)(dst + c * 16) = t;
    }
}

// ---------------- pre-pass B: V fp32 -> V^T bf16, granule-transposed tiles
__global__ __launch_bounds__(256, 2)
void prep_vt_kernel(const float* __restrict__ V, char* __restrict__ ws)
{
    __shared__ unsigned short vt[DD * PSTR];     // [128][64] pad->72
    const int tid  = threadIdx.x;
    const int kvt  = blockIdx.x;
    const int head = blockIdx.y;
    const float* Vh = V + ((size_t)head * LK_N + (size_t)kvt * KVBLK) * DD;
    #pragma unroll
    for (int i = 0; i < 8; ++i) {
        int f = tid + 256 * i;          // float4 id, 2048 per tile
        int r  = f >> 5;                // kv row 0..63
        int c4 = f & 31;                // float4 along D
        float4 x = *(const float4*)(Vh + (size_t)r * DD + c4 * 4);
        vt[(c4 * 4 + 0) * PSTR + r] = f2bf(x.x);
        vt[(c4 * 4 + 1) * PSTR + r] = f2bf(x.y);
        vt[(c4 * 4 + 2) * PSTR + r] = f2bf(x.z);
        vt[(c4 * 4 + 3) * PSTR + r] = f2bf(x.w);
    }
    __syncthreads();
    char* dst = ws + WS_K_BYTES + ((size_t)head * NKV + kvt) * KTILE_BYTES;
    #pragma unroll
    for (int i = 0; i < 4; ++i) {
        int c = tid + 256 * i;
        int g = c >> 7;                 // granule col 0..7 (kv)
        int d = c & 127;                // row (d)
        bf16x8 t = *(const bf16x8*)&vt[d * PSTR + g * 8];
        *(bf16x8*)(dst + c * 16) = t;
    }
}

// ---------------- main kernel: 32x32 MFMA, T15 two-tile pipeline
__global__ __launch_bounds__(256, 2)
void attn_main_kernel(const float* __restrict__ Q, const char* __restrict__ kws,
                      const char* __restrict__ vws, float* __restrict__ O)
{
    extern __shared__ char smem[];   // 80 KiB: K x2, V x3 ring

    const int tid  = threadIdx.x;
    const int lane = tid & 63;
    const int wave = tid >> 6;
    const int l31  = lane & 31;
    const int h    = lane >> 5;     // half: 0/1

    // XCD-aware bijective swizzle: 512 blocks, 8 XCDs, 64-block chunks
    const int bid  = blockIdx.x;
    const int sid  = (bid & 7) * (NQB * NHEADS / 8) + (bid >> 3);
    const int head = sid >> 4;
    const int qb   = sid & 15;

    const float* Qh = Q + (size_t)head * LQ_N * DD;
    float*       Oh = O + (size_t)head * LQ_N * DD;
    const char*  kt_g = kws + (size_t)head * NKV * KTILE_BYTES;
    const char*  vt_g = vws + (size_t)head * NKV * KTILE_BYTES;

    // ---- Q^T B-fragments: lane holds Q[q = qrow][d = 16*kd + 8*h + j]
    const int qrow = qb * QBLK + wave * 32 + l31;
    bf16x8 qf[8];
    {
        const float* qp = Qh + (size_t)qrow * DD + 8 * h;
        #pragma unroll
        for (int kd = 0; kd < 8; ++kd) {
            float4 a = *(const float4*)(qp + 16 * kd);
            float4 b = *(const float4*)(qp + 16 * kd + 4);
            bf16x8 t;
            t[0] = (short)f2bf(a.x); t[1] = (short)f2bf(a.y);
            t[2] = (short)f2bf(a.z); t[3] = (short)f2bf(a.w);
            t[4] = (short)f2bf(b.x); t[5] = (short)f2bf(b.y);
            t[6] = (short)f2bf(b.z); t[7] = (short)f2bf(b.w);
            qf[kd] = t;
        }
    }
    asm volatile("s_waitcnt vmcnt(0)" ::: "memory");  // drain Q loads

    f32x16 o_acc[4];
    #pragma unroll
    for (int nt = 0; nt < 4; ++nt)
        #pragma unroll
        for (int i = 0; i < 16; ++i) o_acc[nt][i] = 0.f;
    float m_run = -1e30f, l_run = 0.f;

    // stage tile t: K -> kbuf[t&1], V -> vbuf[t%3]
    auto issue = [&](int t) {
        const char* ks = kt_g + (size_t)t * KTILE_BYTES;
        const char* vs = vt_g + (size_t)t * KTILE_BYTES;
        const char* kl = smem + KB_OFF(t & 1);
        const char* vl = smem + VB_OFF(t % 3);
        #pragma unroll
        for (int i = 0; i < 4; ++i) {
            int off = (tid + 256 * i) * 16;
            gld16(ks + off, kl + off);
            gld16(vs + off, vl + off);
        }
    };

    // QK^T for one tile: s0 <- kv rows 0..31, s1 <- 32..63
    auto do_qk = [&](f32x16& s0, f32x16& s1, const char* kb) {
        #pragma unroll
        for (int i = 0; i < 16; ++i) { s0[i] = 0.f; s1[i] = 0.f; }
        __builtin_amdgcn_s_setprio(1);
        #pragma unroll
        for (int kd = 0; kd < 8; ++kd) {
            int g = 2 * kd + h;
            bf16x8 kf0 = *(const bf16x8*)(kb + ((g * 64 + l31) << 4));
            bf16x8 kf1 = *(const bf16x8*)(kb + ((g * 64 + 32 + l31) << 4));
            s0 = __builtin_amdgcn_mfma_f32_32x32x16_bf16(kf0, qf[kd], s0, 0, 0, 0);
            s1 = __builtin_amdgcn_mfma_f32_32x32x16_bf16(kf1, qf[kd], s1, 0, 0, 0);
        }
        __builtin_amdgcn_s_setprio(0);
    };

    // softmax + P-frag + PV for one (previous) tile; reads V from vb
    auto do_smpv = [&](f32x16& s0, f32x16& s1, const char* vb) {
        float pmax = s0[0];
        #pragma unroll
        for (int i = 1; i < 16; ++i) pmax = fmaxf(pmax, s0[i]);
        #pragma unroll
        for (int i = 0; i < 16; ++i) pmax = fmaxf(pmax, s1[i]);
        pmax = fmaxf(pmax, __shfl_xor(pmax, 32));

        if (!__all(pmax <= m_run + 8.0f)) {     // defer-max (T13)
            float mn = fmaxf(m_run, pmax);
            float al = EXP2F(m_run - mn);
            m_run = mn;
            l_run *= al;
            #pragma unroll
            for (int nt = 0; nt < 4; ++nt)
                #pragma unroll
                for (int i = 0; i < 16; ++i) o_acc[nt][i] *= al;
        }
        float sum = 0.f;
        #pragma unroll
        for (int i = 0; i < 16; ++i) { s0[i] = EXP2F(s0[i] - m_run); sum += s0[i]; }
        #pragma unroll
        for (int i = 0; i < 16; ++i) { s1[i] = EXP2F(s1[i] - m_run); sum += s1[i]; }
        sum += __shfl_xor(sum, 32);
        l_run += sum;

        bf16x8 pf0 = make_pfrag(s0[0], s0[1], s0[2],  s0[3],  s0[4],  s0[5],  s0[6],  s0[7]);
        bf16x8 pf1 = make_pfrag(s0[8], s0[9], s0[10], s0[11], s0[12], s0[13], s0[14], s0[15]);
        bf16x8 pf2 = make_pfrag(s1[0], s1[1], s1[2],  s1[3],  s1[4],  s1[5],  s1[6],  s1[7]);
        bf16x8 pf3 = make_pfrag(s1[8], s1[9], s1[10], s1[11], s1[12], s1[13], s1[14], s1[15]);

        __builtin_amdgcn_s_setprio(1);
        #pragma unroll
        for (int nt = 0; nt < 4; ++nt) {
            int d = 32 * nt + l31;
            bf16x8 vf0 = *(const bf16x8*)(vb + (((0 + h) * 128 + d) << 4));
            bf16x8 vf1 = *(const bf16x8*)(vb + (((2 + h) * 128 + d) << 4));
            bf16x8 vf2 = *(const bf16x8*)(vb + (((4 + h) * 128 + d) << 4));
            bf16x8 vf3 = *(const bf16x8*)(vb + (((6 + h) * 128 + d) << 4));
            o_acc[nt] = __builtin_amdgcn_mfma_f32_32x32x16_bf16(vf0, pf0, o_acc[nt], 0, 0, 0);
            o_acc[nt] = __builtin_amdgcn_mfma_f32_32x32x16_bf16(vf1, pf1, o_acc[nt], 0, 0, 0);
            o_acc[nt] = __builtin_amdgcn_mfma_f32_32x32x16_bf16(vf2, pf2, o_acc[nt], 0, 0, 0);
            o_acc[nt] = __builtin_amdgcn_mfma_f32_32x32x16_bf16(vf3, pf3, o_acc[nt], 0, 0, 0);
        }
        __builtin_amdgcn_s_setprio(0);
    };

    f32x16 sA0, sA1, sB0, sB1;   // named two-tile score state (rule #20)

    issue(0);
    issue(1);

    // ---- t = 0 peel: QK only
    asm volatile("s_waitcnt vmcnt(8)" ::: "memory");
    __builtin_amdgcn_s_barrier();
    do_qk(sA0, sA1, smem + KB_OFF(0));
    __builtin_amdgcn_s_barrier();
    issue(2);

    // ---- main pipeline, unrolled by 2 (t odd, then t+1 even)
    for (int t = 1; t < NKV - 1; t += 2) {
        asm volatile("s_waitcnt vmcnt(8)" ::: "memory");
        __builtin_amdgcn_s_barrier();
        do_qk(sB0, sB1, smem + KB_OFF(1));
        do_smpv(sA0, sA1, smem + VB_OFF((t - 1) % 3));
        __builtin_amdgcn_s_barrier();
        issue(t + 2);

        asm volatile("s_waitcnt vmcnt(8)" ::: "memory");
        __builtin_amdgcn_s_barrier();
        do_qk(sA0, sA1, smem + KB_OFF(0));
        do_smpv(sB0, sB1, smem + VB_OFF(t % 3));
        __builtin_amdgcn_s_barrier();
        if (t + 3 < NKV) issue(t + 3);
    }

    // ---- t = NKV-1 (odd) peel
    asm volatile("s_waitcnt vmcnt(0)" ::: "memory");
    __builtin_amdgcn_s_barrier();
    do_qk(sB0, sB1, smem + KB_OFF(1));
    do_smpv(sA0, sA1, smem + VB_OFF((NKV - 2) % 3));
    // ---- epilogue softmax+PV for the last tile
    do_smpv(sB0, sB1, smem + VB_OFF((NKV - 1) % 3));

    // ---- write O: lane owns col q = qrow
    float inv = 1.0f / l_run;
    float* op = Oh + (size_t)qrow * DD;
    #pragma unroll
    for (int nt = 0; nt < 4; ++nt)
        #pragma unroll
        for (int p = 0; p < 4; ++p) {
            int dbase = 32 * nt + 8 * p + 4 * h;
            float4 w;
            w.x = o_acc[nt][4 * p + 0] * inv;
            w.y = o_acc[nt][4 * p + 1] * inv;
            w.z = o_acc[nt][4 * p + 2] * inv;
            w.w = o_acc[nt][4 * p + 3] * inv;
            *(float4*)(op + dbase) = w;
        }
}

// ================= fallback (round-1 kernel, used if ws too small) ==========
#define KSTRIDE  136
#define VTSTRIDE 40
#define FKV 32

__global__ __launch_bounds__(256, 2)
void attn_fwd_fallback(const float* __restrict__ Q, const float* __restrict__ K,
                       const float* __restrict__ V, float* __restrict__ O)
{
    __shared__ unsigned short k_lds[FKV * KSTRIDE];
    __shared__ unsigned short vt_lds[DD * VTSTRIDE];
    __shared__ unsigned short p_lds2[4 * 16 * VTSTRIDE];

    const int tid  = threadIdx.x;
    const int lane = tid & 63;
    const int wave = tid >> 6;
    const int head = blockIdx.y;
    const int qb   = blockIdx.x;

    const float* Qh = Q + (size_t)head * LQ_N * DD;
    const float* Kh = K + (size_t)head * LK_N * DD;
    const float* Vh = V + (size_t)head * LK_N * DD;
    float*       Oh = O + (size_t)head * LQ_N * DD;

    const int r16 = lane & 15;
    const int g   = lane >> 4;

    const int qrow = qb * 64 + wave * 16 + r16;
    bf16x8 qf[4];
    {
        const float* qp = Qh + (size_t)qrow * DD + 8 * g;
        #pragma unroll
        for (int kt = 0; kt < 4; ++kt) {
            float4 a = *(const float4*)(qp + 32 * kt);
            float4 b = *(const float4*)(qp + 32 * kt + 4);
            bf16x8 t;
            t[0] = (short)f2bf(a.x * SCALE); t[1] = (short)f2bf(a.y * SCALE);
            t[2] = (short)f2bf(a.z * SCALE); t[3] = (short)f2bf(a.w * SCALE);
            t[4] = (short)f2bf(b.x * SCALE); t[5] = (short)f2bf(b.y * SCALE);
            t[6] = (short)f2bf(b.z * SCALE); t[7] = (short)f2bf(b.w * SCALE);
            qf[kt] = t;
        }
    }

    f32x4 o_acc[8];
    #pragma unroll
    for (int dt = 0; dt < 8; ++dt) o_acc[dt] = (f32x4){0.f, 0.f, 0.f, 0.f};
    float m_run[4], l_run[4];
    #pragma unroll
    for (int r = 0; r < 4; ++r) { m_run[r] = -1e30f; l_run[r] = 0.f; }

    for (int kv = 0; kv < LK_N / FKV; ++kv) {
        const float* Kt = Kh + (size_t)kv * FKV * DD;
        const float* Vt = Vh + (size_t)kv * FKV * DD;
        __syncthreads();
        #pragma unroll
        for (int i = 0; i < 4; ++i) {
            int f = tid + 256 * i;
            int row = f >> 5, colf = f & 31;
            float4 x = *(const float4*)(Kt + (size_t)row * DD + colf * 4);
            ushort4 pk;
            pk.x = f2bf(x.x); pk.y = f2bf(x.y); pk.z = f2bf(x.z); pk.w = f2bf(x.w);
            *(ushort4*)(&k_lds[row * KSTRIDE + colf * 4]) = pk;
        }
        #pragma unroll
        for (int i = 0; i < 4; ++i) {
            int f = tid + 256 * i;
            int row = f >> 5, colf = f & 31;
            float4 x = *(const float4*)(Vt + (size_t)row * DD + colf * 4);
            vt_lds[(colf * 4 + 0) * VTSTRIDE + row] = f2bf(x.x);
            vt_lds[(colf * 4 + 1) * VTSTRIDE + row] = f2bf(x.y);
            vt_lds[(colf * 4 + 2) * VTSTRIDE + row] = f2bf(x.z);
            vt_lds[(colf * 4 + 3) * VTSTRIDE + row] = f2bf(x.w);
        }
        __syncthreads();

        f32x4 s0 = (f32x4){0.f,0.f,0.f,0.f};
        f32x4 s1 = (f32x4){0.f,0.f,0.f,0.f};
        #pragma unroll
        for (int kt = 0; kt < 4; ++kt) {
            bf16x8 kf0 = *(const bf16x8*)&k_lds[(r16)      * KSTRIDE + 32 * kt + 8 * g];
            bf16x8 kf1 = *(const bf16x8*)&k_lds[(16 + r16) * KSTRIDE + 32 * kt + 8 * g];
            s0 = __builtin_amdgcn_mfma_f32_16x16x32_bf16(qf[kt], kf0, s0, 0, 0, 0);
            s1 = __builtin_amdgcn_mfma_f32_16x16x32_bf16(qf[kt], kf1, s1, 0, 0, 0);
        }

        float alpha[4];
        f32x4 p0, p1;
        #pragma unroll
        for (int r = 0; r < 4; ++r) {
            float t = fmaxf(s0[r], s1[r]);
            t = fmaxf(t, __shfl_xor(t, 1));
            t = fmaxf(t, __shfl_xor(t, 2));
            t = fmaxf(t, __shfl_xor(t, 4));
            t = fmaxf(t, __shfl_xor(t, 8));
            float mn = fmaxf(m_run[r], t);
            alpha[r] = __expf(m_run[r] - mn);
            m_run[r] = mn;
            p0[r] = __expf(s0[r] - mn);
            p1[r] = __expf(s1[r] - mn);
            float su = p0[r] + p1[r];
            su += __shfl_xor(su, 1);
            su += __shfl_xor(su, 2);
            su += __shfl_xor(su, 4);
            su += __shfl_xor(su, 8);
            l_run[r] = l_run[r] * alpha[r] + su;
        }

        unsigned short* pw = &p_lds2[wave * 16 * VTSTRIDE];
        #pragma unroll
        for (int r = 0; r < 4; ++r) {
            int row = 4 * g + r;
            pw[row * VTSTRIDE + r16]      = f2bf(p0[r]);
            pw[row * VTSTRIDE + 16 + r16] = f2bf(p1[r]);
        }
        bf16x8 pf = *(const bf16x8*)&pw[r16 * VTSTRIDE + 8 * g];

        #pragma unroll
        for (int dt = 0; dt < 8; ++dt) {
            #pragma unroll
            for (int r = 0; r < 4; ++r) o_acc[dt][r] *= alpha[r];
        }
        #pragma unroll
        for (int dt = 0; dt < 8; ++dt) {
            bf16x8 vf = *(const bf16x8*)&vt_lds[(16 * dt + r16) * VTSTRIDE + 8 * g];
            o_acc[dt] = __builtin_amdgcn_mfma_f32_16x16x32_bf16(pf, vf, o_acc[dt], 0, 0, 0);
        }
    }

    #pragma unroll
    for (int r = 0; r < 4; ++r) {
        float inv = 1.0f / l_run[r];
        int row = qb * 64 + wave * 16 + 4 * g + r;
        float* op = Oh + (size_t)row * DD + r16;
        #pragma unroll
        for (int dt = 0; dt < 8; ++dt)
            op[16 * dt] = o_acc[dt][r] * inv;
    }
}

extern "C" void kernel_launch(void* const* d_in, const int* in_sizes, int n_in,
                              void* d_out, int out_size, void* d_ws, size_t ws_size,
                              hipStream_t stream) {
    const float* q = (const float*)d_in[0];
    const float* k = (const float*)d_in[1];
    const float* v = (const float*)d_in[2];
    float* o = (float*)d_out;

    hipError_t attr_ok = hipFuncSetAttribute(
        (const void*)attn_main_kernel,
        hipFuncAttributeMaxDynamicSharedMemorySize, SMEM_MAIN);

    if (ws_size >= WS_NEED && attr_ok == hipSuccess) {
        char* ws = (char*)d_ws;
        prep_k_kernel <<<dim3(NKV, NHEADS), 256, 0, stream>>>(k, ws);
        prep_vt_kernel<<<dim3(NKV, NHEADS), 256, 0, stream>>>(v, ws);
        attn_main_kernel<<<dim3(NQB * NHEADS), 256, SMEM_MAIN, stream>>>(
            q, ws, ws + WS_K_BYTES, o);
    } else {
        attn_fwd_fallback<<<dim3(LQ_N / 64, NHEADS), 256, 0, stream>>>(q, k, v, o);
    }
}